// Round 1
// baseline (9281.848 us; speedup 1.0000x reference)
//
#include <hip/hip_runtime.h>
#include <math.h>

// ---------------------------------------------------------------------------
// CANA_nei graph network forward, fp32 baseline.
// Output layout: [10, N, 128] = [src1, xs_s0, xs_s1, trg1, xs_t0, xs_t1,
//                                cf_s0, cf_s1, cf_t0, cf_t1]
// ---------------------------------------------------------------------------

__device__ __forceinline__ float relu_f(float x) { return x > 0.f ? x : 0.f; }

template<int ACT>
__device__ __forceinline__ float act_fn(float x) {
    if (ACT == 1) return 0.5f * x * (1.f + erff(x * 0.70710678118654752f)); // exact GELU
    if (ACT == 2) return x / (1.f + fabsf(x));                              // soft_sign
    return x;
}

// ---------------------------------------------------------------------------
// Generic fp32 GEMM: out[n, 0:128] = act( X0 @ W0 (+ X1 @ W1) (+ bias) )
// X: [nrows, K] row-major, W: [K, 128] row-major.
// Tile: 64 rows x 128 cols per block of 256 threads; thread = 8 rows x 4 cols.
// ---------------------------------------------------------------------------
template<int K, int ACT, bool DUAL, bool BIAS>
__global__ __launch_bounds__(256)
void gemm128_kernel(const float* __restrict__ X0, const float* __restrict__ X1,
                    const float* __restrict__ W0, const float* __restrict__ W1,
                    const float* __restrict__ bias, float* __restrict__ out, int nrows)
{
    __shared__ float xt[32][68];    // [kk][row], pad 68 keeps 16B align + spreads banks
    __shared__ float wt[32][128];   // [kk][col]
    const int t  = threadIdx.x;
    const int tx = t & 31;          // col group -> j0 = tx*4
    const int ty = t >> 5;          // row group -> r0 = ty*8
    const int row0 = blockIdx.x * 64;

    float acc[8][4];
    #pragma unroll
    for (int i = 0; i < 8; ++i)
        #pragma unroll
        for (int c = 0; c < 4; ++c) acc[i][c] = 0.f;

    #pragma unroll 1
    for (int s = 0; s < (DUAL ? 2 : 1); ++s) {
        const float* X = (DUAL && s) ? X1 : X0;
        const float* W = (DUAL && s) ? W1 : W0;
        #pragma unroll 1
        for (int k0 = 0; k0 < K; k0 += 32) {
            // stage X[64][32] transposed into xt[k][r]
            #pragma unroll
            for (int p = 0; p < 8; ++p) {
                int r   = ty + p * 8;
                int row = row0 + r;
                float v = (row < nrows) ? X[(size_t)row * K + k0 + tx] : 0.f;
                xt[tx][r] = v;
            }
            // stage W[32][128]
            {
                int j  = t & 127;
                int kb = t >> 7;
                #pragma unroll
                for (int p = 0; p < 16; ++p) {
                    int kk = kb + p * 2;
                    wt[kk][j] = W[(size_t)(k0 + kk) * 128 + j];
                }
            }
            __syncthreads();
            #pragma unroll 8
            for (int kk = 0; kk < 32; ++kk) {
                float4 w  = *(const float4*)&wt[kk][tx * 4];
                float4 xa = *(const float4*)&xt[kk][ty * 8];
                float4 xb = *(const float4*)&xt[kk][ty * 8 + 4];
                float xr[8] = {xa.x, xa.y, xa.z, xa.w, xb.x, xb.y, xb.z, xb.w};
                #pragma unroll
                for (int i = 0; i < 8; ++i) {
                    acc[i][0] = fmaf(xr[i], w.x, acc[i][0]);
                    acc[i][1] = fmaf(xr[i], w.y, acc[i][1]);
                    acc[i][2] = fmaf(xr[i], w.z, acc[i][2]);
                    acc[i][3] = fmaf(xr[i], w.w, acc[i][3]);
                }
            }
            __syncthreads();
        }
    }

    float b4[4] = {0.f, 0.f, 0.f, 0.f};
    if (BIAS) {
        b4[0] = bias[tx * 4 + 0]; b4[1] = bias[tx * 4 + 1];
        b4[2] = bias[tx * 4 + 2]; b4[3] = bias[tx * 4 + 3];
    }
    #pragma unroll
    for (int i = 0; i < 8; ++i) {
        int row = row0 + ty * 8 + i;
        if (row < nrows) {
            float4 o;
            o.x = act_fn<ACT>(acc[i][0] + b4[0]);
            o.y = act_fn<ACT>(acc[i][1] + b4[1]);
            o.z = act_fn<ACT>(acc[i][2] + b4[2]);
            o.w = act_fn<ACT>(acc[i][3] + b4[3]);
            *(float4*)&out[(size_t)row * 128 + tx * 4] = o;
        }
    }
}

// ---------------------------------------------------------------------------
// Build W40T[40][128]: rows 0..19 = eaW1[0:128,:]^T, rows 20..39 = eaW1[128:256,:]^T
// ---------------------------------------------------------------------------
__global__ void build_w40t(const float* __restrict__ eaW1, float* __restrict__ w40t)
{
    int t = blockIdx.x * 256 + threadIdx.x;
    if (t >= 40 * 128) return;
    int j = t >> 7;       // 0..39
    int k = t & 127;      // 0..127
    w40t[t] = (j < 20) ? eaW1[k * 20 + j] : eaW1[(128 + k) * 20 + (j - 20)];
}

// ---------------------------------------------------------------------------
// P[n][0:40] = x[n][0:128] @ W40T^T   (P1 | P2 node projections of edge MLP L1)
// Block: 32 rows, 256 threads; thread -> (row r = t&31, col set jg + 8i, i<5)
// ---------------------------------------------------------------------------
__global__ __launch_bounds__(256)
void pkern(const float* __restrict__ X, const float* __restrict__ W40T,
           float* __restrict__ P, int nrows)
{
    __shared__ float xst[128][33];   // [k][row], pad 33 -> conflict-free col reads
    __shared__ float wl[40 * 128];
    const int t = threadIdx.x;
    const int row0 = blockIdx.x * 32;

    #pragma unroll
    for (int p = 0; p < 20; ++p) {
        int idx = t + 256 * p;       // 5120
        wl[idx] = W40T[idx];
    }
    #pragma unroll
    for (int p = 0; p < 4; ++p) {
        int idx = t + 256 * p;       // 1024 float4 loads
        int r   = idx >> 5;
        int kq  = idx & 31;
        int row = row0 + r;
        float4 v = make_float4(0.f, 0.f, 0.f, 0.f);
        if (row < nrows) v = *(const float4*)&X[(size_t)row * 128 + kq * 4];
        xst[kq * 4 + 0][r] = v.x;
        xst[kq * 4 + 1][r] = v.y;
        xst[kq * 4 + 2][r] = v.z;
        xst[kq * 4 + 3][r] = v.w;
    }
    __syncthreads();

    const int r  = t & 31;
    const int jg = t >> 5;           // 0..7
    float acc[5] = {0.f, 0.f, 0.f, 0.f, 0.f};
    #pragma unroll 4
    for (int k = 0; k < 128; ++k) {
        float xv = xst[k][r];
        #pragma unroll
        for (int i = 0; i < 5; ++i)
            acc[i] = fmaf(xv, wl[(jg + 8 * i) * 128 + k], acc[i]);
    }
    int row = row0 + r;
    if (row < nrows) {
        #pragma unroll
        for (int i = 0; i < 5; ++i)
            P[(size_t)row * 40 + jg + 8 * i] = acc[i];
    }
}

// ---------------------------------------------------------------------------
// Edge attention tail: att[e] = sigmoid(relu( relu( relu(P1[r]+P2[c]+b1) @W2 +b2 ) @W3 +b3 ))
// ---------------------------------------------------------------------------
__global__ __launch_bounds__(256)
void edge_att_kernel(const float* __restrict__ P,
                     const int* __restrict__ row, const int* __restrict__ col,
                     const float* __restrict__ eab1, const float* __restrict__ eaW2,
                     const float* __restrict__ eab2, const float* __restrict__ eaW3,
                     const float* __restrict__ eab3, float* __restrict__ att, int E)
{
    __shared__ float w2[200], b2s[10], w3s[10], sb1[20], sb3;
    int t = threadIdx.x;
    if (t < 200) w2[t] = eaW2[t];
    if (t < 20)  sb1[t] = eab1[t];
    if (t < 10)  { b2s[t] = eab2[t]; w3s[t] = eaW3[t]; }
    if (t == 0)  sb3 = eab3[0];
    __syncthreads();

    int e = blockIdx.x * 256 + t;
    if (e >= E) return;
    int r = row[e], c = col[e];
    const float* p1 = P + (size_t)r * 40;
    const float* p2 = P + (size_t)c * 40 + 20;

    float h1[20];
    #pragma unroll
    for (int j = 0; j < 20; ++j)
        h1[j] = relu_f(p1[j] + p2[j] + sb1[j]);

    float h3 = sb3;
    #pragma unroll
    for (int j2 = 0; j2 < 10; ++j2) {
        float s = b2s[j2];
        #pragma unroll
        for (int j = 0; j < 20; ++j)
            s = fmaf(h1[j], w2[j * 10 + j2], s);
        h3 = fmaf(relu_f(s), w3s[j2], h3);
    }
    h3 = relu_f(h3);
    att[e] = 1.f / (1.f + expf(-h3));
}

// ---------------------------------------------------------------------------
// Scatter: agg[col[e]] += w(e) * x[row[e]], w = 0.5*att (mode 0) | 1-0.5*att (mode 1)
// 32 threads per edge, float4 per thread, f32 atomics.
// ---------------------------------------------------------------------------
__global__ __launch_bounds__(256)
void scatter_kernel(const float* __restrict__ X, const int* __restrict__ row,
                    const int* __restrict__ col, const float* __restrict__ att,
                    float* __restrict__ agg, int E, int mode)
{
    long long idx = (long long)blockIdx.x * 256 + threadIdx.x;
    if (idx >= (long long)E * 32) return;
    int e = (int)(idx >> 5);
    int q = (int)(idx & 31);
    float a = att[e];
    float w = mode ? (1.f - 0.5f * a) : (0.5f * a);
    int r = row[e], c = col[e];
    float4 v = *(const float4*)&X[(size_t)r * 128 + q * 4];
    float* dst = &agg[(size_t)c * 128 + q * 4];
    atomicAdd(dst + 0, w * v.x);
    atomicAdd(dst + 1, w * v.y);
    atomicAdd(dst + 2, w * v.z);
    atomicAdd(dst + 3, w * v.w);
}

// ---------------------------------------------------------------------------

extern "C" void kernel_launch(void* const* d_in, const int* in_sizes, int n_in,
                              void* d_out, int out_size, void* d_ws, size_t ws_size,
                              hipStream_t stream)
{
    const float* src_fea = (const float*)d_in[0];
    const float* trg_fea = (const float*)d_in[1];
    const int*   src_row = (const int*)d_in[2];
    const int*   src_col = (const int*)d_in[3];
    const int*   trg_row = (const int*)d_in[4];
    const int*   trg_col = (const int*)d_in[5];
    const float* fxW1 = (const float*)d_in[6];
    const float* fxb1 = (const float*)d_in[7];
    const float* fxW2 = (const float*)d_in[8];
    const float* fxb2 = (const float*)d_in[9];
    const float* eaW1 = (const float*)d_in[10];
    const float* eab1 = (const float*)d_in[11];
    const float* eaW2 = (const float*)d_in[12];
    const float* eab2 = (const float*)d_in[13];
    const float* eaW3 = (const float*)d_in[14];
    const float* eab3 = (const float*)d_in[15];
    const float* convWroot = (const float*)d_in[16];
    const float* convWrel  = (const float*)d_in[17];

    const int N = in_sizes[0] / 512;
    const int E = in_sizes[2];

    float* out = (float*)d_out;
    const size_t slot_sz = (size_t)N * 128;
    auto slot = [&](int i) { return out + (size_t)i * slot_sz; };

    // workspace layout
    float* agg  = (float*)d_ws;                  // N*128
    float* P    = agg + slot_sz;                 // N*40
    float* att  = P + (size_t)N * 40;            // E
    float* w40t = att + E;                       // 40*128

    build_w40t<<<(40 * 128 + 255) / 256, 256, 0, stream>>>(eaW1, w40t);

    const int gb = (N + 63) / 64;
    // fx(src): h -> slot6 (scratch, overwritten later by cf_s0), out -> slot0
    gemm128_kernel<512, 1, false, true><<<gb, 256, 0, stream>>>(src_fea, nullptr, fxW1, nullptr, fxb1, slot(6), N);
    gemm128_kernel<128, 1, false, true><<<gb, 256, 0, stream>>>(slot(6), nullptr, fxW2, nullptr, fxb2, slot(0), N);
    // fx(trg): h -> slot6, out -> slot3
    gemm128_kernel<512, 1, false, true><<<gb, 256, 0, stream>>>(trg_fea, nullptr, fxW1, nullptr, fxb1, slot(6), N);
    gemm128_kernel<128, 1, false, true><<<gb, 256, 0, stream>>>(slot(6), nullptr, fxW2, nullptr, fxb2, slot(3), N);

    const int pgrid = (N + 31) / 32;
    const int egrid = (E + 255) / 256;
    const int sgrid = (int)(((long long)E * 32 + 255) / 256);

    for (int b = 0; b < 2; ++b) {
        const int* row = b ? trg_row : src_row;
        const int* col = b ? trg_col : src_col;
        float* x = slot(b ? 3 : 0);
        for (int L = 0; L < 2; ++L) {
            float* xs = slot(b ? 4 + L : 1 + L);
            float* cf = slot(6 + 2 * b + L);
            const float* Wr = convWroot + (size_t)L * 128 * 128;
            const float* Wl = convWrel  + (size_t)L * 128 * 128;

            // edge attention from current x
            pkern<<<pgrid, 256, 0, stream>>>(x, w40t, P, N);
            edge_att_kernel<<<egrid, 256, 0, stream>>>(P, row, col, eab1, eaW2, eab2, eaW3, eab3, att, E);

            // x_new = softsign(x @ Wroot + segsum(wc * x[row]) @ Wrel)
            hipMemsetAsync(agg, 0, slot_sz * sizeof(float), stream);
            scatter_kernel<<<sgrid, 256, 0, stream>>>(x, row, col, att, agg, E, 0);
            gemm128_kernel<128, 2, true, false><<<gb, 256, 0, stream>>>(x, agg, Wr, Wl, nullptr, xs, N);

            // cfd = softsign(x_new @ Wroot + segsum(wo * x_new[row]) @ Wrel)
            hipMemsetAsync(agg, 0, slot_sz * sizeof(float), stream);
            scatter_kernel<<<sgrid, 256, 0, stream>>>(xs, row, col, att, agg, E, 1);
            gemm128_kernel<128, 2, true, false><<<gb, 256, 0, stream>>>(xs, agg, Wr, Wl, nullptr, cf, N);

            x = xs;
        }
    }
}

// Round 2
// 1772.332 us; speedup vs baseline: 5.2371x; 5.2371x over previous
//
#include <hip/hip_runtime.h>
#include <math.h>

// ---------------------------------------------------------------------------
// CANA_nei graph network forward. fp32, CSR-based aggregation (no atomics on
// feature data).
// Output layout: [10, N, 128] = [src1, xs_s0, xs_s1, trg1, xs_t0, xs_t1,
//                                cf_s0, cf_s1, cf_t0, cf_t1]
// ---------------------------------------------------------------------------

__device__ __forceinline__ float relu_f(float x) { return x > 0.f ? x : 0.f; }

template<int ACT>
__device__ __forceinline__ float act_fn(float x) {
    if (ACT == 1) return 0.5f * x * (1.f + erff(x * 0.70710678118654752f)); // exact GELU
    if (ACT == 2) return x / (1.f + fabsf(x));                              // soft_sign
    return x;
}

// ---------------------------------------------------------------------------
// Generic fp32 GEMM: out[n, 0:128] = act( X0 @ W0 (+ X1 @ W1) (+ bias) )
// ---------------------------------------------------------------------------
template<int K, int ACT, bool DUAL, bool BIAS>
__global__ __launch_bounds__(256)
void gemm128_kernel(const float* __restrict__ X0, const float* __restrict__ X1,
                    const float* __restrict__ W0, const float* __restrict__ W1,
                    const float* __restrict__ bias, float* __restrict__ out, int nrows)
{
    __shared__ float xt[32][68];
    __shared__ float wt[32][128];
    const int t  = threadIdx.x;
    const int tx = t & 31;
    const int ty = t >> 5;
    const int row0 = blockIdx.x * 64;

    float acc[8][4];
    #pragma unroll
    for (int i = 0; i < 8; ++i)
        #pragma unroll
        for (int c = 0; c < 4; ++c) acc[i][c] = 0.f;

    #pragma unroll 1
    for (int s = 0; s < (DUAL ? 2 : 1); ++s) {
        const float* X = (DUAL && s) ? X1 : X0;
        const float* W = (DUAL && s) ? W1 : W0;
        #pragma unroll 1
        for (int k0 = 0; k0 < K; k0 += 32) {
            #pragma unroll
            for (int p = 0; p < 8; ++p) {
                int r   = ty + p * 8;
                int row = row0 + r;
                float v = (row < nrows) ? X[(size_t)row * K + k0 + tx] : 0.f;
                xt[tx][r] = v;
            }
            {
                int j  = t & 127;
                int kb = t >> 7;
                #pragma unroll
                for (int p = 0; p < 16; ++p) {
                    int kk = kb + p * 2;
                    wt[kk][j] = W[(size_t)(k0 + kk) * 128 + j];
                }
            }
            __syncthreads();
            #pragma unroll 8
            for (int kk = 0; kk < 32; ++kk) {
                float4 w  = *(const float4*)&wt[kk][tx * 4];
                float4 xa = *(const float4*)&xt[kk][ty * 8];
                float4 xb = *(const float4*)&xt[kk][ty * 8 + 4];
                float xr[8] = {xa.x, xa.y, xa.z, xa.w, xb.x, xb.y, xb.z, xb.w};
                #pragma unroll
                for (int i = 0; i < 8; ++i) {
                    acc[i][0] = fmaf(xr[i], w.x, acc[i][0]);
                    acc[i][1] = fmaf(xr[i], w.y, acc[i][1]);
                    acc[i][2] = fmaf(xr[i], w.z, acc[i][2]);
                    acc[i][3] = fmaf(xr[i], w.w, acc[i][3]);
                }
            }
            __syncthreads();
        }
    }

    float b4[4] = {0.f, 0.f, 0.f, 0.f};
    if (BIAS) {
        b4[0] = bias[tx * 4 + 0]; b4[1] = bias[tx * 4 + 1];
        b4[2] = bias[tx * 4 + 2]; b4[3] = bias[tx * 4 + 3];
    }
    #pragma unroll
    for (int i = 0; i < 8; ++i) {
        int row = row0 + ty * 8 + i;
        if (row < nrows) {
            float4 o;
            o.x = act_fn<ACT>(acc[i][0] + b4[0]);
            o.y = act_fn<ACT>(acc[i][1] + b4[1]);
            o.z = act_fn<ACT>(acc[i][2] + b4[2]);
            o.w = act_fn<ACT>(acc[i][3] + b4[3]);
            *(float4*)&out[(size_t)row * 128 + tx * 4] = o;
        }
    }
}

// ---------------------------------------------------------------------------
__global__ void build_w40t(const float* __restrict__ eaW1, float* __restrict__ w40t)
{
    int t = blockIdx.x * 256 + threadIdx.x;
    if (t >= 40 * 128) return;
    int j = t >> 7;
    int k = t & 127;
    w40t[t] = (j < 20) ? eaW1[k * 20 + j] : eaW1[(128 + k) * 20 + (j - 20)];
}

// ---------------------------------------------------------------------------
// P[n][0:40] = x[n][0:128] @ W40T^T
// ---------------------------------------------------------------------------
__global__ __launch_bounds__(256)
void pkern(const float* __restrict__ X, const float* __restrict__ W40T,
           float* __restrict__ P, int nrows)
{
    __shared__ float xst[128][33];
    __shared__ float wl[40 * 128];
    const int t = threadIdx.x;
    const int row0 = blockIdx.x * 32;

    #pragma unroll
    for (int p = 0; p < 20; ++p) {
        int idx = t + 256 * p;
        wl[idx] = W40T[idx];
    }
    #pragma unroll
    for (int p = 0; p < 4; ++p) {
        int idx = t + 256 * p;
        int r   = idx >> 5;
        int kq  = idx & 31;
        int row = row0 + r;
        float4 v = make_float4(0.f, 0.f, 0.f, 0.f);
        if (row < nrows) v = *(const float4*)&X[(size_t)row * 128 + kq * 4];
        xst[kq * 4 + 0][r] = v.x;
        xst[kq * 4 + 1][r] = v.y;
        xst[kq * 4 + 2][r] = v.z;
        xst[kq * 4 + 3][r] = v.w;
    }
    __syncthreads();

    const int r  = t & 31;
    const int jg = t >> 5;
    float acc[5] = {0.f, 0.f, 0.f, 0.f, 0.f};
    #pragma unroll 4
    for (int k = 0; k < 128; ++k) {
        float xv = xst[k][r];
        #pragma unroll
        for (int i = 0; i < 5; ++i)
            acc[i] = fmaf(xv, wl[(jg + 8 * i) * 128 + k], acc[i]);
    }
    int row = row0 + r;
    if (row < nrows) {
        #pragma unroll
        for (int i = 0; i < 5; ++i)
            P[(size_t)row * 40 + jg + 8 * i] = acc[i];
    }
}

// ---------------------------------------------------------------------------
// Edge attention tail
// ---------------------------------------------------------------------------
__global__ __launch_bounds__(256)
void edge_att_kernel(const float* __restrict__ P,
                     const int* __restrict__ row, const int* __restrict__ col,
                     const float* __restrict__ eab1, const float* __restrict__ eaW2,
                     const float* __restrict__ eab2, const float* __restrict__ eaW3,
                     const float* __restrict__ eab3, float* __restrict__ att, int E)
{
    __shared__ float w2[200], b2s[10], w3s[10], sb1[20], sb3;
    int t = threadIdx.x;
    if (t < 200) w2[t] = eaW2[t];
    if (t < 20)  sb1[t] = eab1[t];
    if (t < 10)  { b2s[t] = eab2[t]; w3s[t] = eaW3[t]; }
    if (t == 0)  sb3 = eab3[0];
    __syncthreads();

    int e = blockIdx.x * 256 + t;
    if (e >= E) return;
    int r = row[e], c = col[e];
    const float* p1 = P + (size_t)r * 40;
    const float* p2 = P + (size_t)c * 40 + 20;

    float h1[20];
    #pragma unroll
    for (int j = 0; j < 20; ++j)
        h1[j] = relu_f(p1[j] + p2[j] + sb1[j]);

    float h3 = sb3;
    #pragma unroll
    for (int j2 = 0; j2 < 10; ++j2) {
        float s = b2s[j2];
        #pragma unroll
        for (int j = 0; j < 20; ++j)
            s = fmaf(h1[j], w2[j * 10 + j2], s);
        h3 = fmaf(relu_f(s), w3s[j2], h3);
    }
    h3 = relu_f(h3);
    att[e] = 1.f / (1.f + expf(-h3));
}

// ---------------------------------------------------------------------------
// CSR build: histogram -> 3-phase scan -> cursor fill
// ---------------------------------------------------------------------------
__global__ void hist_kernel(const int* __restrict__ col, int* __restrict__ deg, int E)
{
    int e = blockIdx.x * 256 + threadIdx.x;
    if (e < E) atomicAdd(&deg[col[e]], 1);
}

__device__ __forceinline__ int block_incl_scan(int v, int* wsum)
{
    int lane = threadIdx.x & 63;
    int w    = threadIdx.x >> 6;
    #pragma unroll
    for (int off = 1; off < 64; off <<= 1) {
        int t = __shfl_up(v, off);
        if (lane >= off) v += t;
    }
    if (lane == 63) wsum[w] = v;
    __syncthreads();
    int add = 0;
    for (int j = 0; j < w; ++j) add += wsum[j];
    return v + add;
}

__global__ __launch_bounds__(256)
void scanA_kernel(const int* __restrict__ deg, int* __restrict__ coff,
                  int* __restrict__ bsum, int N)
{
    __shared__ int wsum[4];
    int i = blockIdx.x * 256 + threadIdx.x;
    int orig = (i < N) ? deg[i] : 0;
    int v = block_incl_scan(orig, wsum);
    if (i < N) coff[i] = v - orig;          // exclusive within chunk
    if (threadIdx.x == 255) bsum[blockIdx.x] = v;
}

__global__ __launch_bounds__(256)
void scanB_kernel(const int* __restrict__ bsum, int* __restrict__ boff, int nb)
{
    __shared__ int wsum[4];
    int tid = threadIdx.x;
    int orig = (tid < nb) ? bsum[tid] : 0;
    int v = block_incl_scan(orig, wsum);
    if (tid < nb) boff[tid] = v - orig;
}

__global__ __launch_bounds__(256)
void scanC_kernel(int* __restrict__ coff, const int* __restrict__ boff,
                  int* __restrict__ cur, int N, int E)
{
    int i = blockIdx.x * 256 + threadIdx.x;
    if (i < N) {
        int v = coff[i] + boff[i >> 8];
        coff[i] = v;
        cur[i]  = v;
    }
    if (i == 0) coff[N] = E;
}

__global__ __launch_bounds__(256)
void fill_kernel(const int* __restrict__ row, const int* __restrict__ col,
                 int* __restrict__ cur, int* __restrict__ eid,
                 int* __restrict__ crow, int E)
{
    int e = blockIdx.x * 256 + threadIdx.x;
    if (e >= E) return;
    int c = col[e];
    int p = atomicAdd(&cur[c], 1);
    eid[p]  = e;
    crow[p] = row[e];
}

// ---------------------------------------------------------------------------
// CSR aggregation: one wave per target node, 2 floats/lane.
// agg[n] = sum_{e: col[e]==n} w(e) * X[row[e]], w = 0.5a | 1-0.5a
// ---------------------------------------------------------------------------
__global__ __launch_bounds__(256)
void agg_kernel(const float* __restrict__ X, const int* __restrict__ coff,
                const int* __restrict__ eid, const int* __restrict__ crow,
                const float* __restrict__ att, float* __restrict__ agg,
                int N, int mode)
{
    int node = (blockIdx.x << 2) + (threadIdx.x >> 6);
    if (node >= N) return;
    int lane = threadIdx.x & 63;
    int p  = coff[node];
    int pe = coff[node + 1];
    float ax = 0.f, ay = 0.f;
    for (; p + 1 < pe; p += 2) {
        int e0 = eid[p],  e1 = eid[p + 1];
        int r0 = crow[p], r1 = crow[p + 1];
        float a0 = att[e0], a1 = att[e1];
        float w0 = mode ? fmaf(-0.5f, a0, 1.f) : 0.5f * a0;
        float w1 = mode ? fmaf(-0.5f, a1, 1.f) : 0.5f * a1;
        float2 v0 = *(const float2*)&X[(size_t)r0 * 128 + lane * 2];
        float2 v1 = *(const float2*)&X[(size_t)r1 * 128 + lane * 2];
        ax = fmaf(w0, v0.x, ax); ay = fmaf(w0, v0.y, ay);
        ax = fmaf(w1, v1.x, ax); ay = fmaf(w1, v1.y, ay);
    }
    if (p < pe) {
        int e0 = eid[p];
        int r0 = crow[p];
        float a0 = att[e0];
        float w0 = mode ? fmaf(-0.5f, a0, 1.f) : 0.5f * a0;
        float2 v0 = *(const float2*)&X[(size_t)r0 * 128 + lane * 2];
        ax = fmaf(w0, v0.x, ax); ay = fmaf(w0, v0.y, ay);
    }
    float2 o; o.x = ax; o.y = ay;
    *(float2*)&agg[(size_t)node * 128 + lane * 2] = o;
}

// ---------------------------------------------------------------------------

extern "C" void kernel_launch(void* const* d_in, const int* in_sizes, int n_in,
                              void* d_out, int out_size, void* d_ws, size_t ws_size,
                              hipStream_t stream)
{
    const float* src_fea = (const float*)d_in[0];
    const float* trg_fea = (const float*)d_in[1];
    const int*   src_row = (const int*)d_in[2];
    const int*   src_col = (const int*)d_in[3];
    const int*   trg_row = (const int*)d_in[4];
    const int*   trg_col = (const int*)d_in[5];
    const float* fxW1 = (const float*)d_in[6];
    const float* fxb1 = (const float*)d_in[7];
    const float* fxW2 = (const float*)d_in[8];
    const float* fxb2 = (const float*)d_in[9];
    const float* eaW1 = (const float*)d_in[10];
    const float* eab1 = (const float*)d_in[11];
    const float* eaW2 = (const float*)d_in[12];
    const float* eab2 = (const float*)d_in[13];
    const float* eaW3 = (const float*)d_in[14];
    const float* eab3 = (const float*)d_in[15];
    const float* convWroot = (const float*)d_in[16];
    const float* convWrel  = (const float*)d_in[17];

    const int N = in_sizes[0] / 512;
    const int E = in_sizes[2];

    float* out = (float*)d_out;
    const size_t slot_sz = (size_t)N * 128;
    auto slot = [&](int i) { return out + (size_t)i * slot_sz; };

    // ---- workspace layout ----
    float* agg  = (float*)d_ws;                  // N*128
    float* P    = agg + slot_sz;                 // N*40
    float* att  = P + (size_t)N * 40;            // E
    float* w40t = att + E;                       // 40*128
    int* ip = (int*)(w40t + 40 * 128);
    int* deg   = ip;            ip += N;         // transient (shared by both builds)
    int* bsum  = ip;            ip += 256;       // transient
    int* boff  = ip;            ip += 256;       // transient
    int* coff[2]; int* curp[2]; int* eid[2]; int* crow[2];
    for (int g = 0; g < 2; ++g) {
        coff[g] = ip; ip += N + 2;
        curp[g] = ip; ip += N;
        eid[g]  = ip; ip += E;
        crow[g] = ip; ip += E;
    }

    build_w40t<<<(40 * 128 + 255) / 256, 256, 0, stream>>>(eaW1, w40t);

    const int gb = (N + 63) / 64;
    // fx(src): h -> slot6 (scratch, later overwritten by cf_s0), out -> slot0
    gemm128_kernel<512, 1, false, true><<<gb, 256, 0, stream>>>(src_fea, nullptr, fxW1, nullptr, fxb1, slot(6), N);
    gemm128_kernel<128, 1, false, true><<<gb, 256, 0, stream>>>(slot(6), nullptr, fxW2, nullptr, fxb2, slot(0), N);
    // fx(trg): h -> slot6, out -> slot3
    gemm128_kernel<512, 1, false, true><<<gb, 256, 0, stream>>>(trg_fea, nullptr, fxW1, nullptr, fxb1, slot(6), N);
    gemm128_kernel<128, 1, false, true><<<gb, 256, 0, stream>>>(slot(6), nullptr, fxW2, nullptr, fxb2, slot(3), N);

    // ---- CSR builds (once per graph; reused by 4 aggregations each) ----
    const int egrid   = (E + 255) / 256;
    const int nchunks = (N + 255) / 256;
    for (int g = 0; g < 2; ++g) {
        const int* row = g ? trg_row : src_row;
        const int* col = g ? trg_col : src_col;
        hipMemsetAsync(deg, 0, (size_t)N * sizeof(int), stream);
        hist_kernel<<<egrid, 256, 0, stream>>>(col, deg, E);
        scanA_kernel<<<nchunks, 256, 0, stream>>>(deg, coff[g], bsum, N);
        scanB_kernel<<<1, 256, 0, stream>>>(bsum, boff, nchunks);
        scanC_kernel<<<nchunks, 256, 0, stream>>>(coff[g], boff, curp[g], N, E);
        fill_kernel<<<egrid, 256, 0, stream>>>(row, col, curp[g], eid[g], crow[g], E);
    }

    const int pgrid = (N + 31) / 32;
    const int agrid = (N + 3) / 4;

    for (int b = 0; b < 2; ++b) {
        const int* row = b ? trg_row : src_row;
        const int* col = b ? trg_col : src_col;
        float* x = slot(b ? 3 : 0);
        for (int L = 0; L < 2; ++L) {
            float* xs = slot(b ? 4 + L : 1 + L);
            float* cf = slot(6 + 2 * b + L);
            const float* Wr = convWroot + (size_t)L * 128 * 128;
            const float* Wl = convWrel  + (size_t)L * 128 * 128;

            // edge attention from current x
            pkern<<<pgrid, 256, 0, stream>>>(x, w40t, P, N);
            edge_att_kernel<<<egrid, 256, 0, stream>>>(P, row, col, eab1, eaW2, eab2, eaW3, eab3, att, E);

            // x_new = softsign(x @ Wroot + segsum(wc * x[row]) @ Wrel)
            agg_kernel<<<agrid, 256, 0, stream>>>(x, coff[b], eid[b], crow[b], att, agg, N, 0);
            gemm128_kernel<128, 2, true, false><<<gb, 256, 0, stream>>>(x, agg, Wr, Wl, nullptr, xs, N);

            // cfd = softsign(x_new @ Wroot + segsum(wo * x_new[row]) @ Wrel)
            agg_kernel<<<agrid, 256, 0, stream>>>(xs, coff[b], eid[b], crow[b], att, agg, N, 1);
            gemm128_kernel<128, 2, true, false><<<gb, 256, 0, stream>>>(xs, agg, Wr, Wl, nullptr, cf, N);

            x = xs;
        }
    }
}

// Round 3
// 928.340 us; speedup vs baseline: 9.9983x; 1.9091x over previous
//
#include <hip/hip_runtime.h>
#include <math.h>
#include <stdint.h>

// ---------------------------------------------------------------------------
// CANA_nei graph network forward. bf16 MFMA GEMMs + CSR aggregation.
// Output layout: [10, N, 128] = [src1, xs_s0, xs_s1, trg1, xs_t0, xs_t1,
//                                cf_s0, cf_s1, cf_t0, cf_t1]
// ---------------------------------------------------------------------------

typedef __attribute__((ext_vector_type(8))) short bh8;   // 8 bf16 (4 VGPRs)
typedef __attribute__((ext_vector_type(4))) float f4;    // MFMA acc frag

__device__ __forceinline__ float relu_f(float x) { return x > 0.f ? x : 0.f; }

__device__ __forceinline__ unsigned short f2bf(float f) {
    union { float f; unsigned u; } v; v.f = f;
    unsigned r = v.u + 0x7FFF + ((v.u >> 16) & 1);   // RNE
    return (unsigned short)(r >> 16);
}
__device__ __forceinline__ float bf2f(unsigned short b) {
    union { unsigned u; float f; } v; v.u = ((unsigned)b) << 16;
    return v.f;
}

template<int ACT>
__device__ __forceinline__ float act_fn(float x) {
    if (ACT == 1) return 0.5f * x * (1.f + erff(x * 0.70710678118654752f)); // exact GELU
    if (ACT == 2) return x / (1.f + fabsf(x));                              // soft_sign
    return x;
}

// ---------------------------------------------------------------------------
// MFMA GEMM: out[M,128] = act( X0 @ W0 (+ X1 @ W1) (+ bias) )
// X row-major [M,K] (fp32 if AF==0, bf16 if AF==1); W*t pre-transposed bf16
// [128][K]. Block: 64 rows x 128 cols, 256 thr = 4 waves (2m x 2n),
// wave = 32x64 via 2x4 frags of v_mfma_f32_16x16x32_bf16.
// Frag layouts (learn_hip verified): A[l&15][8*(l>>4)+j] (contiguous-k b128),
// B^T[n=l&15][k contiguous], C/D row=(l>>4)*4+reg, col=l&15.
// LDS rows padded to 72 bf16 (144 B) -> 2-way bank aliasing (free, m136).
// ---------------------------------------------------------------------------
template<int K, int AF, int ACT, bool DUAL, bool BIAS, bool WF32, bool WB16>
__global__ __launch_bounds__(256, 2)
void mfma_gemm(const void* __restrict__ X0v, const void* __restrict__ X1v,
               const short* __restrict__ W0t, const short* __restrict__ W1t,
               const float* __restrict__ bias,
               float* __restrict__ outf, short* __restrict__ outb, int M)
{
    constexpr int BK  = 64;
    constexpr int LDA = 72;                 // bf16 elems/row incl. pad
    __shared__ short As[64 * LDA];
    __shared__ short Bs[128 * LDA];

    const int t    = threadIdx.x;
    const int row0 = blockIdx.x * 64;
    const int lane = t & 63;
    const int w    = t >> 6;
    const int wr   = w & 1;                 // m half
    const int wc   = w >> 1;                // n half
    const int l15  = lane & 15;
    const int l4   = lane >> 4;

    f4 acc[2][4];
    #pragma unroll
    for (int i = 0; i < 2; ++i)
        #pragma unroll
        for (int j = 0; j < 4; ++j)
            acc[i][j] = (f4){0.f, 0.f, 0.f, 0.f};

    const int ar = t >> 3;                  // staging row 0..31
    const int ac = (t & 7) * 8;             // staging col (elems)

    #pragma unroll 1
    for (int s = 0; s < (DUAL ? 2 : 1); ++s) {
        const float* Xf = (const float*)((DUAL && s) ? X1v : X0v);
        const short* Xb = (const short*)((DUAL && s) ? X1v : X0v);
        const short* Wt = (DUAL && s) ? W1t : W0t;
        #pragma unroll 1
        for (int k0 = 0; k0 < K; k0 += BK) {
            __syncthreads();
            // ---- stage A tile 64x64 (convert fp32->bf16 if AF==0) ----
            #pragma unroll
            for (int p = 0; p < 2; ++p) {
                int r    = ar + p * 32;
                int grow = row0 + r;
                bh8 sv = {0, 0, 0, 0, 0, 0, 0, 0};
                if (AF == 0) {
                    if (grow < M) {
                        const float* src = Xf + (size_t)grow * K + k0 + ac;
                        float4 v0 = *(const float4*)src;
                        float4 v1 = *(const float4*)(src + 4);
                        sv[0] = (short)f2bf(v0.x); sv[1] = (short)f2bf(v0.y);
                        sv[2] = (short)f2bf(v0.z); sv[3] = (short)f2bf(v0.w);
                        sv[4] = (short)f2bf(v1.x); sv[5] = (short)f2bf(v1.y);
                        sv[6] = (short)f2bf(v1.z); sv[7] = (short)f2bf(v1.w);
                    }
                } else {
                    if (grow < M)
                        sv = *(const bh8*)(Xb + (size_t)grow * K + k0 + ac);
                }
                *(bh8*)&As[r * LDA + ac] = sv;
            }
            // ---- stage B tile 128x64 from W^T ----
            #pragma unroll
            for (int p = 0; p < 4; ++p) {
                int r = ar + p * 32;
                *(bh8*)&Bs[r * LDA + ac] =
                    *(const bh8*)(Wt + (size_t)r * K + k0 + ac);
            }
            __syncthreads();
            // ---- MFMA compute ----
            #pragma unroll
            for (int kk = 0; kk < 2; ++kk) {
                bh8 a[2], b[4];
                #pragma unroll
                for (int mi = 0; mi < 2; ++mi)
                    a[mi] = *(const bh8*)&As[(wr*32 + mi*16 + l15) * LDA + kk*32 + l4*8];
                #pragma unroll
                for (int ni = 0; ni < 4; ++ni)
                    b[ni] = *(const bh8*)&Bs[(wc*64 + ni*16 + l15) * LDA + kk*32 + l4*8];
                #pragma unroll
                for (int mi = 0; mi < 2; ++mi)
                    #pragma unroll
                    for (int ni = 0; ni < 4; ++ni)
                        acc[mi][ni] = __builtin_amdgcn_mfma_f32_16x16x32_bf16(
                            a[mi], b[ni], acc[mi][ni], 0, 0, 0);
            }
        }
    }

    // ---- epilogue ----
    #pragma unroll
    for (int mi = 0; mi < 2; ++mi) {
        #pragma unroll
        for (int ni = 0; ni < 4; ++ni) {
            int col = wc * 64 + ni * 16 + l15;
            float bv = BIAS ? bias[col] : 0.f;
            #pragma unroll
            for (int r = 0; r < 4; ++r) {
                int row = row0 + wr * 32 + mi * 16 + l4 * 4 + r;
                if (row < M) {
                    float v = act_fn<ACT>(acc[mi][ni][r] + bv);
                    if (WF32) outf[(size_t)row * 128 + col] = v;
                    if (WB16) outb[(size_t)row * 128 + col] = (short)f2bf(v);
                }
            }
        }
    }
}

// ---------------------------------------------------------------------------
// Weight prep: Wt[n][k] (bf16) <- W[k][n] (fp32), W is [K,128]
// ---------------------------------------------------------------------------
__global__ void prep_wt(const float* __restrict__ W, short* __restrict__ Wt, int K)
{
    int i = blockIdx.x * 256 + threadIdx.x;
    if (i >= K * 128) return;
    int k = i >> 7, n = i & 127;
    Wt[(size_t)n * K + k] = (short)f2bf(W[i]);
}

__global__ void build_w40t(const float* __restrict__ eaW1, float* __restrict__ w40t)
{
    int t = blockIdx.x * 256 + threadIdx.x;
    if (t >= 40 * 128) return;
    int j = t >> 7;
    int k = t & 127;
    w40t[t] = (j < 20) ? eaW1[k * 20 + j] : eaW1[(128 + k) * 20 + (j - 20)];
}

// ---------------------------------------------------------------------------
// P[n][0:40] = x[n][0:128] @ W40T^T   (fp32, reads x from output slots)
// ---------------------------------------------------------------------------
__global__ __launch_bounds__(256)
void pkern(const float* __restrict__ X, const float* __restrict__ W40T,
           float* __restrict__ P, int nrows)
{
    __shared__ float xst[128][33];
    __shared__ float wl[40 * 128];
    const int t = threadIdx.x;
    const int row0 = blockIdx.x * 32;

    #pragma unroll
    for (int p = 0; p < 20; ++p) {
        int idx = t + 256 * p;
        wl[idx] = W40T[idx];
    }
    #pragma unroll
    for (int p = 0; p < 4; ++p) {
        int idx = t + 256 * p;
        int r   = idx >> 5;
        int kq  = idx & 31;
        int row = row0 + r;
        float4 v = make_float4(0.f, 0.f, 0.f, 0.f);
        if (row < nrows) v = *(const float4*)&X[(size_t)row * 128 + kq * 4];
        xst[kq * 4 + 0][r] = v.x;
        xst[kq * 4 + 1][r] = v.y;
        xst[kq * 4 + 2][r] = v.z;
        xst[kq * 4 + 3][r] = v.w;
    }
    __syncthreads();

    const int r  = t & 31;
    const int jg = t >> 5;
    float acc[5] = {0.f, 0.f, 0.f, 0.f, 0.f};
    #pragma unroll 4
    for (int k = 0; k < 128; ++k) {
        float xv = xst[k][r];
        #pragma unroll
        for (int i = 0; i < 5; ++i)
            acc[i] = fmaf(xv, wl[(jg + 8 * i) * 128 + k], acc[i]);
    }
    int row = row0 + r;
    if (row < nrows) {
        #pragma unroll
        for (int i = 0; i < 5; ++i)
            P[(size_t)row * 40 + jg + 8 * i] = acc[i];
    }
}

// ---------------------------------------------------------------------------
// Edge attention tail
// ---------------------------------------------------------------------------
__global__ __launch_bounds__(256)
void edge_att_kernel(const float* __restrict__ P,
                     const int* __restrict__ row, const int* __restrict__ col,
                     const float* __restrict__ eab1, const float* __restrict__ eaW2,
                     const float* __restrict__ eab2, const float* __restrict__ eaW3,
                     const float* __restrict__ eab3, float* __restrict__ att, int E)
{
    __shared__ float w2[200], b2s[10], w3s[10], sb1[20], sb3;
    int t = threadIdx.x;
    if (t < 200) w2[t] = eaW2[t];
    if (t < 20)  sb1[t] = eab1[t];
    if (t < 10)  { b2s[t] = eab2[t]; w3s[t] = eaW3[t]; }
    if (t == 0)  sb3 = eab3[0];
    __syncthreads();

    int e = blockIdx.x * 256 + t;
    if (e >= E) return;
    int r = row[e], c = col[e];
    const float* p1 = P + (size_t)r * 40;
    const float* p2 = P + (size_t)c * 40 + 20;

    float h1[20];
    #pragma unroll
    for (int j = 0; j < 20; ++j)
        h1[j] = relu_f(p1[j] + p2[j] + sb1[j]);

    float h3 = sb3;
    #pragma unroll
    for (int j2 = 0; j2 < 10; ++j2) {
        float s = b2s[j2];
        #pragma unroll
        for (int j = 0; j < 20; ++j)
            s = fmaf(h1[j], w2[j * 10 + j2], s);
        h3 = fmaf(relu_f(s), w3s[j2], h3);
    }
    h3 = relu_f(h3);
    att[e] = 1.f / (1.f + expf(-h3));
}

// ---------------------------------------------------------------------------
// CSR build: histogram -> 3-phase scan -> cursor fill
// ---------------------------------------------------------------------------
__global__ void hist_kernel(const int* __restrict__ col, int* __restrict__ deg, int E)
{
    int e = blockIdx.x * 256 + threadIdx.x;
    if (e < E) atomicAdd(&deg[col[e]], 1);
}

__device__ __forceinline__ int block_incl_scan(int v, int* wsum)
{
    int lane = threadIdx.x & 63;
    int w    = threadIdx.x >> 6;
    #pragma unroll
    for (int off = 1; off < 64; off <<= 1) {
        int t = __shfl_up(v, off);
        if (lane >= off) v += t;
    }
    if (lane == 63) wsum[w] = v;
    __syncthreads();
    int add = 0;
    for (int j = 0; j < w; ++j) add += wsum[j];
    return v + add;
}

__global__ __launch_bounds__(256)
void scanA_kernel(const int* __restrict__ deg, int* __restrict__ coff,
                  int* __restrict__ bsum, int N)
{
    __shared__ int wsum[4];
    int i = blockIdx.x * 256 + threadIdx.x;
    int orig = (i < N) ? deg[i] : 0;
    int v = block_incl_scan(orig, wsum);
    if (i < N) coff[i] = v - orig;
    if (threadIdx.x == 255) bsum[blockIdx.x] = v;
}

__global__ __launch_bounds__(256)
void scanB_kernel(const int* __restrict__ bsum, int* __restrict__ boff, int nb)
{
    __shared__ int wsum[4];
    int tid = threadIdx.x;
    int orig = (tid < nb) ? bsum[tid] : 0;
    int v = block_incl_scan(orig, wsum);
    if (tid < nb) boff[tid] = v - orig;
}

__global__ __launch_bounds__(256)
void scanC_kernel(int* __restrict__ coff, const int* __restrict__ boff,
                  int* __restrict__ cur, int N, int E)
{
    int i = blockIdx.x * 256 + threadIdx.x;
    if (i < N) {
        int v = coff[i] + boff[i >> 8];
        coff[i] = v;
        cur[i]  = v;
    }
    if (i == 0) coff[N] = E;
}

__global__ __launch_bounds__(256)
void fill_kernel(const int* __restrict__ row, const int* __restrict__ col,
                 int* __restrict__ cur, int* __restrict__ eid,
                 int* __restrict__ crow, int E)
{
    int e = blockIdx.x * 256 + threadIdx.x;
    if (e >= E) return;
    int c = col[e];
    int p = atomicAdd(&cur[c], 1);
    eid[p]  = e;
    crow[p] = row[e];
}

// ---------------------------------------------------------------------------
// CSR aggregation (bf16 in/out): one wave per node, 2 cols/lane.
// agg[n] = sum_{e: col[e]==n} w(e) * X[row[e]], w = 0.5a | 1-0.5a
// ---------------------------------------------------------------------------
__global__ __launch_bounds__(256)
void agg_kernel(const short* __restrict__ Xb, const int* __restrict__ coff,
                const int* __restrict__ eid, const int* __restrict__ crow,
                const float* __restrict__ att, short* __restrict__ aggb,
                int N, int mode)
{
    int node = (blockIdx.x << 2) + (threadIdx.x >> 6);
    if (node >= N) return;
    int lane = threadIdx.x & 63;
    int p  = coff[node];
    int pe = coff[node + 1];
    float a0 = 0.f, a1 = 0.f;
    for (; p + 1 < pe; p += 2) {
        int e0 = eid[p],  e1 = eid[p + 1];
        int r0 = crow[p], r1 = crow[p + 1];
        float w0 = att[e0], w1 = att[e1];
        w0 = mode ? fmaf(-0.5f, w0, 1.f) : 0.5f * w0;
        w1 = mode ? fmaf(-0.5f, w1, 1.f) : 0.5f * w1;
        ushort2 v0 = *(const ushort2*)&Xb[(size_t)r0 * 128 + lane * 2];
        ushort2 v1 = *(const ushort2*)&Xb[(size_t)r1 * 128 + lane * 2];
        a0 = fmaf(w0, bf2f(v0.x), a0); a1 = fmaf(w0, bf2f(v0.y), a1);
        a0 = fmaf(w1, bf2f(v1.x), a0); a1 = fmaf(w1, bf2f(v1.y), a1);
    }
    if (p < pe) {
        int e0 = eid[p];
        int r0 = crow[p];
        float w0 = att[e0];
        w0 = mode ? fmaf(-0.5f, w0, 1.f) : 0.5f * w0;
        ushort2 v0 = *(const ushort2*)&Xb[(size_t)r0 * 128 + lane * 2];
        a0 = fmaf(w0, bf2f(v0.x), a0); a1 = fmaf(w0, bf2f(v0.y), a1);
    }
    ushort2 o;
    o.x = f2bf(a0);
    o.y = f2bf(a1);
    *(ushort2*)&aggb[(size_t)node * 128 + lane * 2] = o;
}

// ---------------------------------------------------------------------------

extern "C" void kernel_launch(void* const* d_in, const int* in_sizes, int n_in,
                              void* d_out, int out_size, void* d_ws, size_t ws_size,
                              hipStream_t stream)
{
    const float* src_fea = (const float*)d_in[0];
    const float* trg_fea = (const float*)d_in[1];
    const int*   src_row = (const int*)d_in[2];
    const int*   src_col = (const int*)d_in[3];
    const int*   trg_row = (const int*)d_in[4];
    const int*   trg_col = (const int*)d_in[5];
    const float* fxW1 = (const float*)d_in[6];
    const float* fxb1 = (const float*)d_in[7];
    const float* fxW2 = (const float*)d_in[8];
    const float* fxb2 = (const float*)d_in[9];
    const float* eaW1 = (const float*)d_in[10];
    const float* eab1 = (const float*)d_in[11];
    const float* eaW2 = (const float*)d_in[12];
    const float* eab2 = (const float*)d_in[13];
    const float* eaW3 = (const float*)d_in[14];
    const float* eab3 = (const float*)d_in[15];
    const float* convWroot = (const float*)d_in[16];
    const float* convWrel  = (const float*)d_in[17];

    const int N = in_sizes[0] / 512;
    const int E = in_sizes[2];

    float* out = (float*)d_out;
    const size_t slot_sz = (size_t)N * 128;
    auto slot = [&](int i) { return out + (size_t)i * slot_sz; };

    // ---- workspace layout ----
    float* fp   = (float*)d_ws;
    float* P    = fp; fp += (size_t)N * 40;
    float* att  = fp; fp += E;
    float* w40t = fp; fp += 40 * 128;
    int* ip   = (int*)fp;
    int* deg  = ip; ip += N;
    int* bsum = ip; ip += 256;
    int* boff = ip; ip += 256;
    int* coff[2]; int* curp[2]; int* eid[2]; int* crow[2];
    for (int g = 0; g < 2; ++g) {
        coff[g] = ip; ip += N + 2;
        curp[g] = ip; ip += N;
        eid[g]  = ip; ip += E;
        crow[g] = ip; ip += E;
    }
    short* sp = (short*)((((uintptr_t)ip) + 255) & ~(uintptr_t)255);
    short* xb0   = sp; sp += slot_sz;        // bf16 src1
    short* xb1   = sp; sp += slot_sz;        // bf16 trg1
    short* xs0b  = sp; sp += slot_sz;        // bf16 xs (layer even) — doubles as fx hidden h
    short* xs1b  = sp; sp += slot_sz;        // bf16 xs (layer odd)
    short* aggb  = sp; sp += slot_sz;        // bf16 aggregation
    short* fxW1t = sp; sp += 128 * 512;
    short* fxW2t = sp; sp += 128 * 128;
    short* wrt   = sp; sp += 2 * 128 * 128;
    short* wlt   = sp; sp += 2 * 128 * 128;

    // ---- weight prep ----
    build_w40t<<<(40 * 128 + 255) / 256, 256, 0, stream>>>(eaW1, w40t);
    prep_wt<<<(512 * 128 + 255) / 256, 256, 0, stream>>>(fxW1, fxW1t, 512);
    prep_wt<<<(128 * 128 + 255) / 256, 256, 0, stream>>>(fxW2, fxW2t, 128);
    for (int L = 0; L < 2; ++L) {
        prep_wt<<<64, 256, 0, stream>>>(convWroot + (size_t)L * 16384, wrt + (size_t)L * 16384, 128);
        prep_wt<<<64, 256, 0, stream>>>(convWrel  + (size_t)L * 16384, wlt + (size_t)L * 16384, 128);
    }

    const int gb = (N + 63) / 64;
    short* h = xs0b;   // fx hidden, dead before xs0b's first conv write
    // fx(src): h(bf16) -> slot0 fp32 + xb0 bf16
    mfma_gemm<512, 0, 1, false, true, false, true><<<gb, 256, 0, stream>>>(src_fea, nullptr, fxW1t, nullptr, fxb1, nullptr, h, N);
    mfma_gemm<128, 1, 1, false, true, true,  true><<<gb, 256, 0, stream>>>(h, nullptr, fxW2t, nullptr, fxb2, slot(0), xb0, N);
    // fx(trg)
    mfma_gemm<512, 0, 1, false, true, false, true><<<gb, 256, 0, stream>>>(trg_fea, nullptr, fxW1t, nullptr, fxb1, nullptr, h, N);
    mfma_gemm<128, 1, 1, false, true, true,  true><<<gb, 256, 0, stream>>>(h, nullptr, fxW2t, nullptr, fxb2, slot(3), xb1, N);

    // ---- CSR builds (once per graph; reused by 4 aggregations each) ----
    const int egrid   = (E + 255) / 256;
    const int nchunks = (N + 255) / 256;
    for (int g = 0; g < 2; ++g) {
        const int* row = g ? trg_row : src_row;
        const int* col = g ? trg_col : src_col;
        hipMemsetAsync(deg, 0, (size_t)N * sizeof(int), stream);
        hist_kernel<<<egrid, 256, 0, stream>>>(col, deg, E);
        scanA_kernel<<<nchunks, 256, 0, stream>>>(deg, coff[g], bsum, N);
        scanB_kernel<<<1, 256, 0, stream>>>(bsum, boff, nchunks);
        scanC_kernel<<<nchunks, 256, 0, stream>>>(coff[g], boff, curp[g], N, E);
        fill_kernel<<<egrid, 256, 0, stream>>>(row, col, curp[g], eid[g], crow[g], E);
    }

    const int pgrid = (N + 31) / 32;
    const int agrid = (N + 3) / 4;

    for (int b = 0; b < 2; ++b) {
        const int* row = b ? trg_row : src_row;
        const int* col = b ? trg_col : src_col;
        float* xf      = slot(b ? 3 : 0);
        short* xbcur   = b ? xb1 : xb0;
        for (int L = 0; L < 2; ++L) {
            float* xs = slot(b ? 4 + L : 1 + L);
            float* cf = slot(6 + 2 * b + L);
            short* xsb = L ? xs1b : xs0b;
            const short* WrT = wrt + (size_t)L * 16384;
            const short* WlT = wlt + (size_t)L * 16384;

            // edge attention from current x (fp32 slot)
            pkern<<<pgrid, 256, 0, stream>>>(xf, w40t, P, N);
            edge_att_kernel<<<egrid, 256, 0, stream>>>(P, row, col, eab1, eaW2, eab2, eaW3, eab3, att, E);

            // x_new = softsign(x @ Wroot + segsum(wc * x[row]) @ Wrel)
            agg_kernel<<<agrid, 256, 0, stream>>>(xbcur, coff[b], eid[b], crow[b], att, aggb, N, 0);
            mfma_gemm<128, 1, 2, true, false, true, true><<<gb, 256, 0, stream>>>(xbcur, aggb, WrT, WlT, nullptr, xs, xsb, N);

            // cfd = softsign(x_new @ Wroot + segsum(wo * x_new[row]) @ Wrel)
            agg_kernel<<<agrid, 256, 0, stream>>>(xsb, coff[b], eid[b], crow[b], att, aggb, N, 1);
            mfma_gemm<128, 1, 2, true, false, true, false><<<gb, 256, 0, stream>>>(xsb, aggb, WrT, WlT, nullptr, cf, nullptr, N);

            xf = xs; xbcur = xsb;
        }
    }
}

// Round 4
// 794.637 us; speedup vs baseline: 11.6806x; 1.1683x over previous
//
#include <hip/hip_runtime.h>
#include <math.h>
#include <stdint.h>

// ---------------------------------------------------------------------------
// CANA_nei graph network forward. bf16 MFMA GEMMs + CSR aggregation,
// bf16 P-projection for the edge-attention MLP.
// Output layout: [10, N, 128] = [src1, xs_s0, xs_s1, trg1, xs_t0, xs_t1,
//                                cf_s0, cf_s1, cf_t0, cf_t1]
// ---------------------------------------------------------------------------

typedef __attribute__((ext_vector_type(8))) short bh8;   // 8 bf16 (4 VGPRs)
typedef __attribute__((ext_vector_type(4))) float f4;    // MFMA acc frag

__device__ __forceinline__ float relu_f(float x) { return x > 0.f ? x : 0.f; }

__device__ __forceinline__ unsigned short f2bf(float f) {
    union { float f; unsigned u; } v; v.f = f;
    unsigned r = v.u + 0x7FFF + ((v.u >> 16) & 1);   // RNE
    return (unsigned short)(r >> 16);
}
__device__ __forceinline__ float bf2f(unsigned short b) {
    union { unsigned u; float f; } v; v.u = ((unsigned)b) << 16;
    return v.f;
}

template<int ACT>
__device__ __forceinline__ float act_fn(float x) {
    if (ACT == 1) return 0.5f * x * (1.f + erff(x * 0.70710678118654752f)); // exact GELU
    if (ACT == 2) return x / (1.f + fabsf(x));                              // soft_sign
    return x;
}

// ---------------------------------------------------------------------------
// MFMA GEMM: out[M,128] = act( X0 @ W0 (+ X1 @ W1) (+ bias) )
// X row-major [M,K] (fp32 if AF==0, bf16 if AF==1); W*t pre-transposed bf16
// [128][K]. Block: 64 rows x 128 cols, 256 thr = 4 waves (2m x 2n),
// wave = 32x64 via 2x4 frags of v_mfma_f32_16x16x32_bf16.
// ---------------------------------------------------------------------------
template<int K, int AF, int ACT, bool DUAL, bool BIAS, bool WF32, bool WB16>
__global__ __launch_bounds__(256, 2)
void mfma_gemm(const void* __restrict__ X0v, const void* __restrict__ X1v,
               const short* __restrict__ W0t, const short* __restrict__ W1t,
               const float* __restrict__ bias,
               float* __restrict__ outf, short* __restrict__ outb, int M)
{
    constexpr int BK  = 64;
    constexpr int LDA = 72;                 // bf16 elems/row incl. pad
    __shared__ short As[64 * LDA];
    __shared__ short Bs[128 * LDA];

    const int t    = threadIdx.x;
    const int row0 = blockIdx.x * 64;
    const int lane = t & 63;
    const int w    = t >> 6;
    const int wr   = w & 1;                 // m half
    const int wc   = w >> 1;                // n half
    const int l15  = lane & 15;
    const int l4   = lane >> 4;

    f4 acc[2][4];
    #pragma unroll
    for (int i = 0; i < 2; ++i)
        #pragma unroll
        for (int j = 0; j < 4; ++j)
            acc[i][j] = (f4){0.f, 0.f, 0.f, 0.f};

    const int ar = t >> 3;                  // staging row 0..31
    const int ac = (t & 7) * 8;             // staging col (elems)

    #pragma unroll 1
    for (int s = 0; s < (DUAL ? 2 : 1); ++s) {
        const float* Xf = (const float*)((DUAL && s) ? X1v : X0v);
        const short* Xb = (const short*)((DUAL && s) ? X1v : X0v);
        const short* Wt = (DUAL && s) ? W1t : W0t;
        #pragma unroll 1
        for (int k0 = 0; k0 < K; k0 += BK) {
            __syncthreads();
            // ---- stage A tile 64x64 (convert fp32->bf16 if AF==0) ----
            #pragma unroll
            for (int p = 0; p < 2; ++p) {
                int r    = ar + p * 32;
                int grow = row0 + r;
                bh8 sv = {0, 0, 0, 0, 0, 0, 0, 0};
                if (AF == 0) {
                    if (grow < M) {
                        const float* src = Xf + (size_t)grow * K + k0 + ac;
                        float4 v0 = *(const float4*)src;
                        float4 v1 = *(const float4*)(src + 4);
                        sv[0] = (short)f2bf(v0.x); sv[1] = (short)f2bf(v0.y);
                        sv[2] = (short)f2bf(v0.z); sv[3] = (short)f2bf(v0.w);
                        sv[4] = (short)f2bf(v1.x); sv[5] = (short)f2bf(v1.y);
                        sv[6] = (short)f2bf(v1.z); sv[7] = (short)f2bf(v1.w);
                    }
                } else {
                    if (grow < M)
                        sv = *(const bh8*)(Xb + (size_t)grow * K + k0 + ac);
                }
                *(bh8*)&As[r * LDA + ac] = sv;
            }
            // ---- stage B tile 128x64 from W^T ----
            #pragma unroll
            for (int p = 0; p < 4; ++p) {
                int r = ar + p * 32;
                *(bh8*)&Bs[r * LDA + ac] =
                    *(const bh8*)(Wt + (size_t)r * K + k0 + ac);
            }
            __syncthreads();
            // ---- MFMA compute ----
            #pragma unroll
            for (int kk = 0; kk < 2; ++kk) {
                bh8 a[2], b[4];
                #pragma unroll
                for (int mi = 0; mi < 2; ++mi)
                    a[mi] = *(const bh8*)&As[(wr*32 + mi*16 + l15) * LDA + kk*32 + l4*8];
                #pragma unroll
                for (int ni = 0; ni < 4; ++ni)
                    b[ni] = *(const bh8*)&Bs[(wc*64 + ni*16 + l15) * LDA + kk*32 + l4*8];
                #pragma unroll
                for (int mi = 0; mi < 2; ++mi)
                    #pragma unroll
                    for (int ni = 0; ni < 4; ++ni)
                        acc[mi][ni] = __builtin_amdgcn_mfma_f32_16x16x32_bf16(
                            a[mi], b[ni], acc[mi][ni], 0, 0, 0);
            }
        }
    }

    // ---- epilogue ----
    #pragma unroll
    for (int mi = 0; mi < 2; ++mi) {
        #pragma unroll
        for (int ni = 0; ni < 4; ++ni) {
            int col = wc * 64 + ni * 16 + l15;
            float bv = BIAS ? bias[col] : 0.f;
            #pragma unroll
            for (int r = 0; r < 4; ++r) {
                int row = row0 + wr * 32 + mi * 16 + l4 * 4 + r;
                if (row < M) {
                    float v = act_fn<ACT>(acc[mi][ni][r] + bv);
                    if (WF32) outf[(size_t)row * 128 + col] = v;
                    if (WB16) outb[(size_t)row * 128 + col] = (short)f2bf(v);
                }
            }
        }
    }
}

// ---------------------------------------------------------------------------
// P[n][0:48] = x[n][0:128] @ W40^T  (bf16 in/out, MFMA). W40 bf16 [48][128],
// rows 40..47 zero. P stored bf16 stride 48 (96 B rows).
// Block: 64 rows, 4 waves = 4m x 1n; wave = 16 rows x 48 cols (3 n-frags).
// ---------------------------------------------------------------------------
__global__ __launch_bounds__(256, 2)
void pkern_mfma(const short* __restrict__ Xb, const short* __restrict__ W40,
                short* __restrict__ P, int M)
{
    constexpr int LDA = 72;
    __shared__ short As[64 * LDA];
    __shared__ short Bs[48 * LDA];

    const int t    = threadIdx.x;
    const int row0 = blockIdx.x * 64;
    const int lane = t & 63;
    const int w    = t >> 6;                // m quarter: rows w*16..
    const int l15  = lane & 15;
    const int l4   = lane >> 4;

    f4 acc[3];
    #pragma unroll
    for (int i = 0; i < 3; ++i) acc[i] = (f4){0.f, 0.f, 0.f, 0.f};

    const int ar = t >> 3;
    const int ac = (t & 7) * 8;

    #pragma unroll 1
    for (int k0 = 0; k0 < 128; k0 += 64) {
        __syncthreads();
        #pragma unroll
        for (int p = 0; p < 2; ++p) {
            int r    = ar + p * 32;
            int grow = row0 + r;
            bh8 sv = {0, 0, 0, 0, 0, 0, 0, 0};
            if (grow < M)
                sv = *(const bh8*)(Xb + (size_t)grow * 128 + k0 + ac);
            *(bh8*)&As[r * LDA + ac] = sv;
        }
        #pragma unroll
        for (int p = 0; p < 2; ++p) {
            int r = ar + p * 32;
            if (r < 48)
                *(bh8*)&Bs[r * LDA + ac] =
                    *(const bh8*)(W40 + (size_t)r * 128 + k0 + ac);
        }
        __syncthreads();
        #pragma unroll
        for (int kk = 0; kk < 2; ++kk) {
            bh8 a = *(const bh8*)&As[(w * 16 + l15) * LDA + kk * 32 + l4 * 8];
            #pragma unroll
            for (int ni = 0; ni < 3; ++ni) {
                bh8 b = *(const bh8*)&Bs[(ni * 16 + l15) * LDA + kk * 32 + l4 * 8];
                acc[ni] = __builtin_amdgcn_mfma_f32_16x16x32_bf16(a, b, acc[ni], 0, 0, 0);
            }
        }
    }

    #pragma unroll
    for (int ni = 0; ni < 3; ++ni) {
        int col = ni * 16 + l15;
        #pragma unroll
        for (int r = 0; r < 4; ++r) {
            int row = row0 + w * 16 + l4 * 4 + r;
            if (row < M)
                P[(size_t)row * 48 + col] = (short)f2bf(acc[ni][r]);
        }
    }
}

// ---------------------------------------------------------------------------
// Weight prep
// ---------------------------------------------------------------------------
__global__ void prep_wt(const float* __restrict__ W, short* __restrict__ Wt, int K)
{
    int i = blockIdx.x * 256 + threadIdx.x;
    if (i >= K * 128) return;
    int k = i >> 7, n = i & 127;
    Wt[(size_t)n * K + k] = (short)f2bf(W[i]);
}

// W40 bf16 [48][128]: row j<20 = eaW1[0:128, j]^T, 20<=j<40 = eaW1[128:256, j-20]^T, else 0
__global__ void build_w40b(const float* __restrict__ eaW1, short* __restrict__ w40b)
{
    int t = blockIdx.x * 256 + threadIdx.x;
    if (t >= 48 * 128) return;
    int j = t >> 7;
    int k = t & 127;
    float v = 0.f;
    if (j < 20)      v = eaW1[k * 20 + j];
    else if (j < 40) v = eaW1[(128 + k) * 20 + (j - 20)];
    w40b[t] = (short)f2bf(v);
}

// ---------------------------------------------------------------------------
// Edge attention tail (bf16 P gather)
// ---------------------------------------------------------------------------
__global__ __launch_bounds__(256)
void edge_att_kernel(const short* __restrict__ P,
                     const int* __restrict__ row, const int* __restrict__ col,
                     const float* __restrict__ eab1, const float* __restrict__ eaW2,
                     const float* __restrict__ eab2, const float* __restrict__ eaW3,
                     const float* __restrict__ eab3, float* __restrict__ att, int E)
{
    __shared__ float w2[200], b2s[10], w3s[10], sb1[20], sb3;
    int t = threadIdx.x;
    if (t < 200) w2[t] = eaW2[t];
    if (t < 20)  sb1[t] = eab1[t];
    if (t < 10)  { b2s[t] = eab2[t]; w3s[t] = eaW3[t]; }
    if (t == 0)  sb3 = eab3[0];
    __syncthreads();

    int e = blockIdx.x * 256 + t;
    if (e >= E) return;
    int r = row[e], c = col[e];
    const unsigned short* p1 = (const unsigned short*)P + (size_t)r * 48;
    const unsigned short* p2 = (const unsigned short*)P + (size_t)c * 48 + 20;

    float h1[20];
    #pragma unroll
    for (int j = 0; j < 10; ++j) {
        ushort2 u1 = *(const ushort2*)&p1[2 * j];
        ushort2 u2 = *(const ushort2*)&p2[2 * j];
        h1[2 * j]     = relu_f(bf2f(u1.x) + bf2f(u2.x) + sb1[2 * j]);
        h1[2 * j + 1] = relu_f(bf2f(u1.y) + bf2f(u2.y) + sb1[2 * j + 1]);
    }

    float h3 = sb3;
    #pragma unroll
    for (int j2 = 0; j2 < 10; ++j2) {
        float s = b2s[j2];
        #pragma unroll
        for (int j = 0; j < 20; ++j)
            s = fmaf(h1[j], w2[j * 10 + j2], s);
        h3 = fmaf(relu_f(s), w3s[j2], h3);
    }
    h3 = relu_f(h3);
    att[e] = 1.f / (1.f + expf(-h3));
}

// ---------------------------------------------------------------------------
// CSR build: histogram -> 3-phase scan -> cursor fill
// ---------------------------------------------------------------------------
__global__ void hist_kernel(const int* __restrict__ col, int* __restrict__ deg, int E)
{
    int e = blockIdx.x * 256 + threadIdx.x;
    if (e < E) atomicAdd(&deg[col[e]], 1);
}

__device__ __forceinline__ int block_incl_scan(int v, int* wsum)
{
    int lane = threadIdx.x & 63;
    int w    = threadIdx.x >> 6;
    #pragma unroll
    for (int off = 1; off < 64; off <<= 1) {
        int t = __shfl_up(v, off);
        if (lane >= off) v += t;
    }
    if (lane == 63) wsum[w] = v;
    __syncthreads();
    int add = 0;
    for (int j = 0; j < w; ++j) add += wsum[j];
    return v + add;
}

__global__ __launch_bounds__(256)
void scanA_kernel(const int* __restrict__ deg, int* __restrict__ coff,
                  int* __restrict__ bsum, int N)
{
    __shared__ int wsum[4];
    int i = blockIdx.x * 256 + threadIdx.x;
    int orig = (i < N) ? deg[i] : 0;
    int v = block_incl_scan(orig, wsum);
    if (i < N) coff[i] = v - orig;
    if (threadIdx.x == 255) bsum[blockIdx.x] = v;
}

__global__ __launch_bounds__(256)
void scanB_kernel(const int* __restrict__ bsum, int* __restrict__ boff, int nb)
{
    __shared__ int wsum[4];
    int tid = threadIdx.x;
    int orig = (tid < nb) ? bsum[tid] : 0;
    int v = block_incl_scan(orig, wsum);
    if (tid < nb) boff[tid] = v - orig;
}

__global__ __launch_bounds__(256)
void scanC_kernel(int* __restrict__ coff, const int* __restrict__ boff,
                  int* __restrict__ cur, int N, int E)
{
    int i = blockIdx.x * 256 + threadIdx.x;
    if (i < N) {
        int v = coff[i] + boff[i >> 8];
        coff[i] = v;
        cur[i]  = v;
    }
    if (i == 0) coff[N] = E;
}

__global__ __launch_bounds__(256)
void fill_kernel(const int* __restrict__ row, const int* __restrict__ col,
                 int* __restrict__ cur, int* __restrict__ eid,
                 int* __restrict__ crow, int E)
{
    int e = blockIdx.x * 256 + threadIdx.x;
    if (e >= E) return;
    int c = col[e];
    int p = atomicAdd(&cur[c], 1);
    eid[p]  = e;
    crow[p] = row[e];
}

// ---------------------------------------------------------------------------
// CSR aggregation (bf16 in/out): one wave per node, 2 cols/lane, 4-deep ILP.
// agg[n] = sum_{e: col[e]==n} w(e) * X[row[e]], w = 0.5a | 1-0.5a
// ---------------------------------------------------------------------------
__global__ __launch_bounds__(256)
void agg_kernel(const short* __restrict__ Xb, const int* __restrict__ coff,
                const int* __restrict__ eid, const int* __restrict__ crow,
                const float* __restrict__ att, short* __restrict__ aggb,
                int N, int mode)
{
    int node = (blockIdx.x << 2) + (threadIdx.x >> 6);
    if (node >= N) return;
    int lane = threadIdx.x & 63;
    int p  = coff[node];
    int pe = coff[node + 1];
    float a0 = 0.f, a1 = 0.f;
    for (; p + 3 < pe; p += 4) {
        int e0 = eid[p],  e1 = eid[p + 1], e2 = eid[p + 2], e3 = eid[p + 3];
        int r0 = crow[p], r1 = crow[p + 1], r2 = crow[p + 2], r3 = crow[p + 3];
        float w0 = att[e0], w1 = att[e1], w2 = att[e2], w3 = att[e3];
        w0 = mode ? fmaf(-0.5f, w0, 1.f) : 0.5f * w0;
        w1 = mode ? fmaf(-0.5f, w1, 1.f) : 0.5f * w1;
        w2 = mode ? fmaf(-0.5f, w2, 1.f) : 0.5f * w2;
        w3 = mode ? fmaf(-0.5f, w3, 1.f) : 0.5f * w3;
        ushort2 v0 = *(const ushort2*)&Xb[(size_t)r0 * 128 + lane * 2];
        ushort2 v1 = *(const ushort2*)&Xb[(size_t)r1 * 128 + lane * 2];
        ushort2 v2 = *(const ushort2*)&Xb[(size_t)r2 * 128 + lane * 2];
        ushort2 v3 = *(const ushort2*)&Xb[(size_t)r3 * 128 + lane * 2];
        a0 = fmaf(w0, bf2f(v0.x), a0); a1 = fmaf(w0, bf2f(v0.y), a1);
        a0 = fmaf(w1, bf2f(v1.x), a0); a1 = fmaf(w1, bf2f(v1.y), a1);
        a0 = fmaf(w2, bf2f(v2.x), a0); a1 = fmaf(w2, bf2f(v2.y), a1);
        a0 = fmaf(w3, bf2f(v3.x), a0); a1 = fmaf(w3, bf2f(v3.y), a1);
    }
    for (; p < pe; ++p) {
        int e0 = eid[p];
        int r0 = crow[p];
        float w0 = att[e0];
        w0 = mode ? fmaf(-0.5f, w0, 1.f) : 0.5f * w0;
        ushort2 v0 = *(const ushort2*)&Xb[(size_t)r0 * 128 + lane * 2];
        a0 = fmaf(w0, bf2f(v0.x), a0); a1 = fmaf(w0, bf2f(v0.y), a1);
    }
    ushort2 o;
    o.x = f2bf(a0);
    o.y = f2bf(a1);
    *(ushort2*)&aggb[(size_t)node * 128 + lane * 2] = o;
}

// ---------------------------------------------------------------------------

extern "C" void kernel_launch(void* const* d_in, const int* in_sizes, int n_in,
                              void* d_out, int out_size, void* d_ws, size_t ws_size,
                              hipStream_t stream)
{
    const float* src_fea = (const float*)d_in[0];
    const float* trg_fea = (const float*)d_in[1];
    const int*   src_row = (const int*)d_in[2];
    const int*   src_col = (const int*)d_in[3];
    const int*   trg_row = (const int*)d_in[4];
    const int*   trg_col = (const int*)d_in[5];
    const float* fxW1 = (const float*)d_in[6];
    const float* fxb1 = (const float*)d_in[7];
    const float* fxW2 = (const float*)d_in[8];
    const float* fxb2 = (const float*)d_in[9];
    const float* eaW1 = (const float*)d_in[10];
    const float* eab1 = (const float*)d_in[11];
    const float* eaW2 = (const float*)d_in[12];
    const float* eab2 = (const float*)d_in[13];
    const float* eaW3 = (const float*)d_in[14];
    const float* eab3 = (const float*)d_in[15];
    const float* convWroot = (const float*)d_in[16];
    const float* convWrel  = (const float*)d_in[17];

    const int N = in_sizes[0] / 512;
    const int E = in_sizes[2];

    float* out = (float*)d_out;
    const size_t slot_sz = (size_t)N * 128;
    auto slot = [&](int i) { return out + (size_t)i * slot_sz; };

    // ---- workspace layout ----
    float* fp  = (float*)d_ws;
    float* att = fp; fp += E;
    int* ip   = (int*)fp;
    int* deg  = ip; ip += N;
    int* bsum = ip; ip += 256;
    int* boff = ip; ip += 256;
    int* coff[2]; int* curp[2]; int* eid[2]; int* crow[2];
    for (int g = 0; g < 2; ++g) {
        coff[g] = ip; ip += N + 2;
        curp[g] = ip; ip += N;
        eid[g]  = ip; ip += E;
        crow[g] = ip; ip += E;
    }
    short* sp = (short*)((((uintptr_t)ip) + 255) & ~(uintptr_t)255);
    short* xb0   = sp; sp += slot_sz;        // bf16 src1
    short* xb1   = sp; sp += slot_sz;        // bf16 trg1
    short* xs0b  = sp; sp += slot_sz;        // bf16 xs (layer even) — doubles as fx hidden h
    short* xs1b  = sp; sp += slot_sz;        // bf16 xs (layer odd)
    short* aggb  = sp; sp += slot_sz;        // bf16 aggregation
    short* Pb    = sp; sp += (size_t)N * 48; // bf16 node projections, stride 48
    short* w40b  = sp; sp += 48 * 128;
    short* fxW1t = sp; sp += 128 * 512;
    short* fxW2t = sp; sp += 128 * 128;
    short* wrt   = sp; sp += 2 * 128 * 128;
    short* wlt   = sp; sp += 2 * 128 * 128;

    // ---- weight prep ----
    build_w40b<<<(48 * 128 + 255) / 256, 256, 0, stream>>>(eaW1, w40b);
    prep_wt<<<(512 * 128 + 255) / 256, 256, 0, stream>>>(fxW1, fxW1t, 512);
    prep_wt<<<(128 * 128 + 255) / 256, 256, 0, stream>>>(fxW2, fxW2t, 128);
    for (int L = 0; L < 2; ++L) {
        prep_wt<<<64, 256, 0, stream>>>(convWroot + (size_t)L * 16384, wrt + (size_t)L * 16384, 128);
        prep_wt<<<64, 256, 0, stream>>>(convWrel  + (size_t)L * 16384, wlt + (size_t)L * 16384, 128);
    }

    const int gb = (N + 63) / 64;
    short* h = xs0b;   // fx hidden, dead before xs0b's first conv write
    // fx(src): h(bf16) -> slot0 fp32 + xb0 bf16
    mfma_gemm<512, 0, 1, false, true, false, true><<<gb, 256, 0, stream>>>(src_fea, nullptr, fxW1t, nullptr, fxb1, nullptr, h, N);
    mfma_gemm<128, 1, 1, false, true, true,  true><<<gb, 256, 0, stream>>>(h, nullptr, fxW2t, nullptr, fxb2, slot(0), xb0, N);
    // fx(trg)
    mfma_gemm<512, 0, 1, false, true, false, true><<<gb, 256, 0, stream>>>(trg_fea, nullptr, fxW1t, nullptr, fxb1, nullptr, h, N);
    mfma_gemm<128, 1, 1, false, true, true,  true><<<gb, 256, 0, stream>>>(h, nullptr, fxW2t, nullptr, fxb2, slot(3), xb1, N);

    // ---- CSR builds (once per graph; reused by 4 aggregations each) ----
    const int egrid   = (E + 255) / 256;
    const int nchunks = (N + 255) / 256;
    for (int g = 0; g < 2; ++g) {
        const int* row = g ? trg_row : src_row;
        const int* col = g ? trg_col : src_col;
        hipMemsetAsync(deg, 0, (size_t)N * sizeof(int), stream);
        hist_kernel<<<egrid, 256, 0, stream>>>(col, deg, E);
        scanA_kernel<<<nchunks, 256, 0, stream>>>(deg, coff[g], bsum, N);
        scanB_kernel<<<1, 256, 0, stream>>>(bsum, boff, nchunks);
        scanC_kernel<<<nchunks, 256, 0, stream>>>(coff[g], boff, curp[g], N, E);
        fill_kernel<<<egrid, 256, 0, stream>>>(row, col, curp[g], eid[g], crow[g], E);
    }

    const int agrid = (N + 3) / 4;

    for (int b = 0; b < 2; ++b) {
        const int* row = b ? trg_row : src_row;
        const int* col = b ? trg_col : src_col;
        short* xbcur   = b ? xb1 : xb0;
        for (int L = 0; L < 2; ++L) {
            float* xs = slot(b ? 4 + L : 1 + L);
            float* cf = slot(6 + 2 * b + L);
            short* xsb = L ? xs1b : xs0b;
            const short* WrT = wrt + (size_t)L * 16384;
            const short* WlT = wlt + (size_t)L * 16384;

            // edge attention from current x (bf16)
            pkern_mfma<<<gb, 256, 0, stream>>>(xbcur, w40b, Pb, N);
            edge_att_kernel<<<egrid, 256, 0, stream>>>(Pb, row, col, eab1, eaW2, eab2, eaW3, eab3, att, E);

            // x_new = softsign(x @ Wroot + segsum(wc * x[row]) @ Wrel)
            agg_kernel<<<agrid, 256, 0, stream>>>(xbcur, coff[b], eid[b], crow[b], att, aggb, N, 0);
            mfma_gemm<128, 1, 2, true, false, true, true><<<gb, 256, 0, stream>>>(xbcur, aggb, WrT, WlT, nullptr, xs, xsb, N);

            // cfd = softsign(x_new @ Wroot + segsum(wo * x_new[row]) @ Wrel)
            agg_kernel<<<agrid, 256, 0, stream>>>(xsb, coff[b], eid[b], crow[b], att, aggb, N, 1);
            mfma_gemm<128, 1, 2, true, false, true, false><<<gb, 256, 0, stream>>>(xsb, aggb, WrT, WlT, nullptr, cf, nullptr, N);

            xbcur = xsb;
        }
    }
}

// Round 5
// 689.879 us; speedup vs baseline: 13.4543x; 1.1518x over previous
//
#include <hip/hip_runtime.h>
#include <math.h>
#include <stdint.h>

// ---------------------------------------------------------------------------
// CANA_nei graph network forward. bf16 MFMA GEMMs + CSR aggregation.
// Both graphs (src/trg) processed in every dispatch (branch fusion).
// Output layout: [10, N, 128] = [src1, xs_s0, xs_s1, trg1, xs_t0, xs_t1,
//                                cf_s0, cf_s1, cf_t0, cf_t1]
// ---------------------------------------------------------------------------

typedef __attribute__((ext_vector_type(8))) short bh8;   // 8 bf16 (4 VGPRs)
typedef __attribute__((ext_vector_type(4))) float f4;    // MFMA acc frag

__device__ __forceinline__ float relu_f(float x) { return x > 0.f ? x : 0.f; }

__device__ __forceinline__ unsigned short f2bf(float f) {
    union { float f; unsigned u; } v; v.f = f;
    unsigned r = v.u + 0x7FFF + ((v.u >> 16) & 1);   // RNE
    return (unsigned short)(r >> 16);
}
__device__ __forceinline__ float bf2f(unsigned short b) {
    union { unsigned u; float f; } v; v.u = ((unsigned)b) << 16;
    return v.f;
}

template<int ACT>
__device__ __forceinline__ float act_fn(float x) {
    if (ACT == 1) return 0.5f * x * (1.f + erff(x * 0.70710678118654752f)); // exact GELU
    if (ACT == 2) return x / (1.f + fabsf(x));                              // soft_sign
    return x;
}

// ---------------------------------------------------------------------------
// MFMA GEMM, dual-graph: blocks [0,half) -> graph A, [half,2*half) -> graph B.
// out[M,128] = act( X0 @ W0 (+ X1 @ W1) (+ bias) )
// X row-major [M,K] (fp32 if AF==0, bf16 if AF==1); W*t pre-transposed bf16
// [128][K]. Per-graph block: 64 rows x 128 cols, 4 waves (2m x 2n),
// wave = 32x64 via 2x4 frags of v_mfma_f32_16x16x32_bf16.
// ---------------------------------------------------------------------------
template<int K, int AF, int ACT, bool DUAL, bool BIAS, bool WF32, bool WB16>
__global__ __launch_bounds__(256, 2)
void mfma_gemm(const void* __restrict__ X0a, const void* __restrict__ X1a,
               const void* __restrict__ X0b, const void* __restrict__ X1b,
               const short* __restrict__ W0t, const short* __restrict__ W1t,
               const float* __restrict__ bias,
               float* __restrict__ outfA, short* __restrict__ outbA,
               float* __restrict__ outfB, short* __restrict__ outbB, int M)
{
    constexpr int BK  = 64;
    constexpr int LDA = 72;                 // bf16 elems/row incl. pad
    __shared__ short As[64 * LDA];
    __shared__ short Bs[128 * LDA];

    const int half = gridDim.x >> 1;
    int bid = blockIdx.x;
    const int g1 = bid >= half;
    bid -= g1 ? half : 0;
    const void* X0v = g1 ? X0b : X0a;
    const void* X1v = g1 ? X1b : X1a;
    float* outf = g1 ? outfB : outfA;
    short* outb = g1 ? outbB : outbA;

    const int t    = threadIdx.x;
    const int row0 = bid * 64;
    const int lane = t & 63;
    const int w    = t >> 6;
    const int wr   = w & 1;                 // m half
    const int wc   = w >> 1;                // n half
    const int l15  = lane & 15;
    const int l4   = lane >> 4;

    f4 acc[2][4];
    #pragma unroll
    for (int i = 0; i < 2; ++i)
        #pragma unroll
        for (int j = 0; j < 4; ++j)
            acc[i][j] = (f4){0.f, 0.f, 0.f, 0.f};

    const int ar = t >> 3;                  // staging row 0..31
    const int ac = (t & 7) * 8;             // staging col (elems)

    #pragma unroll 1
    for (int s = 0; s < (DUAL ? 2 : 1); ++s) {
        const float* Xf = (const float*)((DUAL && s) ? X1v : X0v);
        const short* Xb = (const short*)((DUAL && s) ? X1v : X0v);
        const short* Wt = (DUAL && s) ? W1t : W0t;
        #pragma unroll 1
        for (int k0 = 0; k0 < K; k0 += BK) {
            __syncthreads();
            // ---- stage A tile 64x64 (convert fp32->bf16 if AF==0) ----
            #pragma unroll
            for (int p = 0; p < 2; ++p) {
                int r    = ar + p * 32;
                int grow = row0 + r;
                bh8 sv = {0, 0, 0, 0, 0, 0, 0, 0};
                if (AF == 0) {
                    if (grow < M) {
                        const float* src = Xf + (size_t)grow * K + k0 + ac;
                        float4 v0 = *(const float4*)src;
                        float4 v1 = *(const float4*)(src + 4);
                        sv[0] = (short)f2bf(v0.x); sv[1] = (short)f2bf(v0.y);
                        sv[2] = (short)f2bf(v0.z); sv[3] = (short)f2bf(v0.w);
                        sv[4] = (short)f2bf(v1.x); sv[5] = (short)f2bf(v1.y);
                        sv[6] = (short)f2bf(v1.z); sv[7] = (short)f2bf(v1.w);
                    }
                } else {
                    if (grow < M)
                        sv = *(const bh8*)(Xb + (size_t)grow * K + k0 + ac);
                }
                *(bh8*)&As[r * LDA + ac] = sv;
            }
            // ---- stage B tile 128x64 from W^T ----
            #pragma unroll
            for (int p = 0; p < 4; ++p) {
                int r = ar + p * 32;
                *(bh8*)&Bs[r * LDA + ac] =
                    *(const bh8*)(Wt + (size_t)r * K + k0 + ac);
            }
            __syncthreads();
            // ---- MFMA compute ----
            #pragma unroll
            for (int kk = 0; kk < 2; ++kk) {
                bh8 a[2], b[4];
                #pragma unroll
                for (int mi = 0; mi < 2; ++mi)
                    a[mi] = *(const bh8*)&As[(wr*32 + mi*16 + l15) * LDA + kk*32 + l4*8];
                #pragma unroll
                for (int ni = 0; ni < 4; ++ni)
                    b[ni] = *(const bh8*)&Bs[(wc*64 + ni*16 + l15) * LDA + kk*32 + l4*8];
                #pragma unroll
                for (int mi = 0; mi < 2; ++mi)
                    #pragma unroll
                    for (int ni = 0; ni < 4; ++ni)
                        acc[mi][ni] = __builtin_amdgcn_mfma_f32_16x16x32_bf16(
                            a[mi], b[ni], acc[mi][ni], 0, 0, 0);
            }
        }
    }

    // ---- epilogue ----
    #pragma unroll
    for (int mi = 0; mi < 2; ++mi) {
        #pragma unroll
        for (int ni = 0; ni < 4; ++ni) {
            int col = wc * 64 + ni * 16 + l15;
            float bv = BIAS ? bias[col] : 0.f;
            #pragma unroll
            for (int r = 0; r < 4; ++r) {
                int row = row0 + wr * 32 + mi * 16 + l4 * 4 + r;
                if (row < M) {
                    float v = act_fn<ACT>(acc[mi][ni][r] + bv);
                    if (WF32) outf[(size_t)row * 128 + col] = v;
                    if (WB16) outb[(size_t)row * 128 + col] = (short)f2bf(v);
                }
            }
        }
    }
}

// ---------------------------------------------------------------------------
// P[n][0:64] = x[n][0:128] @ W56^T  (bf16, MFMA), dual-graph.
// W56 bf16 [64][128]: rows 0..19 = P1 weights, rows 32..51 = P2 weights,
// rest zero. P stored bf16 stride 64 (128 B rows): P1 at 0, P2 at elem 32.
// Block: 64 rows, 4 waves = 4m x 1n; wave = 16 rows x 64 cols (4 n-frags).
// ---------------------------------------------------------------------------
__global__ __launch_bounds__(256, 2)
void pkern_both(const short* __restrict__ XbS, const short* __restrict__ XbT,
                const short* __restrict__ W56,
                short* __restrict__ PS, short* __restrict__ PT, int M)
{
    constexpr int LDA = 72;
    __shared__ short As[64 * LDA];
    __shared__ short Bs[64 * LDA];

    const int half = gridDim.x >> 1;
    int bid = blockIdx.x;
    const int g1 = bid >= half;
    bid -= g1 ? half : 0;
    const short* Xb = g1 ? XbT : XbS;
    short* P        = g1 ? PT  : PS;

    const int t    = threadIdx.x;
    const int row0 = bid * 64;
    const int lane = t & 63;
    const int w    = t >> 6;                // m quarter
    const int l15  = lane & 15;
    const int l4   = lane >> 4;

    f4 acc[4];
    #pragma unroll
    for (int i = 0; i < 4; ++i) acc[i] = (f4){0.f, 0.f, 0.f, 0.f};

    const int ar = t >> 3;
    const int ac = (t & 7) * 8;

    #pragma unroll 1
    for (int k0 = 0; k0 < 128; k0 += 64) {
        __syncthreads();
        #pragma unroll
        for (int p = 0; p < 2; ++p) {
            int r    = ar + p * 32;
            int grow = row0 + r;
            bh8 sv = {0, 0, 0, 0, 0, 0, 0, 0};
            if (grow < M)
                sv = *(const bh8*)(Xb + (size_t)grow * 128 + k0 + ac);
            *(bh8*)&As[r * LDA + ac] = sv;
        }
        #pragma unroll
        for (int p = 0; p < 2; ++p) {
            int r = ar + p * 32;
            *(bh8*)&Bs[r * LDA + ac] =
                *(const bh8*)(W56 + (size_t)r * 128 + k0 + ac);
        }
        __syncthreads();
        #pragma unroll
        for (int kk = 0; kk < 2; ++kk) {
            bh8 a = *(const bh8*)&As[(w * 16 + l15) * LDA + kk * 32 + l4 * 8];
            #pragma unroll
            for (int ni = 0; ni < 4; ++ni) {
                bh8 b = *(const bh8*)&Bs[(ni * 16 + l15) * LDA + kk * 32 + l4 * 8];
                acc[ni] = __builtin_amdgcn_mfma_f32_16x16x32_bf16(a, b, acc[ni], 0, 0, 0);
            }
        }
    }

    #pragma unroll
    for (int ni = 0; ni < 4; ++ni) {
        int col = ni * 16 + l15;
        #pragma unroll
        for (int r = 0; r < 4; ++r) {
            int row = row0 + w * 16 + l4 * 4 + r;
            if (row < M)
                P[(size_t)row * 64 + col] = (short)f2bf(acc[ni][r]);
        }
    }
}

// ---------------------------------------------------------------------------
// One-shot weight prep: w56 + all bf16 transposed weights, one kernel.
// ---------------------------------------------------------------------------
__global__ void prep_all(const float* __restrict__ eaW1, const float* __restrict__ fxW1,
                         const float* __restrict__ fxW2, const float* __restrict__ convWroot,
                         const float* __restrict__ convWrel,
                         short* __restrict__ w56, short* __restrict__ fxW1t,
                         short* __restrict__ fxW2t, short* __restrict__ wrt,
                         short* __restrict__ wlt)
{
    int i = blockIdx.x * 256 + threadIdx.x;
    if (i < 64 * 128) {
        int j = i >> 7, k = i & 127;
        float v = 0.f;
        if (j < 20)                  v = eaW1[k * 20 + j];
        else if (j >= 32 && j < 52)  v = eaW1[(128 + k) * 20 + (j - 32)];
        w56[i] = (short)f2bf(v);
        return;
    }
    i -= 64 * 128;
    if (i < 512 * 128) {
        int k = i >> 7, n = i & 127;
        fxW1t[(size_t)n * 512 + k] = (short)f2bf(fxW1[i]);
        return;
    }
    i -= 512 * 128;
    if (i < 128 * 128) {
        int k = i >> 7, n = i & 127;
        fxW2t[n * 128 + k] = (short)f2bf(fxW2[i]);
        return;
    }
    i -= 128 * 128;
    if (i < 2 * 128 * 128) {
        int L = i >> 14, r = i & 16383;
        int k = r >> 7, n = r & 127;
        wrt[L * 16384 + n * 128 + k] = (short)f2bf(convWroot[i]);
        return;
    }
    i -= 2 * 128 * 128;
    if (i < 2 * 128 * 128) {
        int L = i >> 14, r = i & 16383;
        int k = r >> 7, n = r & 127;
        wlt[L * 16384 + n * 128 + k] = (short)f2bf(convWrel[i]);
    }
}

// ---------------------------------------------------------------------------
// Edge attention tail (dual-graph, vectorized bf16 P gather).
// Writes att directly in CSR order: attc[epos[e]] = sigmoid(...)
// ---------------------------------------------------------------------------
__global__ __launch_bounds__(256)
void edge_att_both(const short* __restrict__ PS, const short* __restrict__ PT,
                   const int* __restrict__ rowS, const int* __restrict__ colS,
                   const int* __restrict__ rowT, const int* __restrict__ colT,
                   const int* __restrict__ eposS, const int* __restrict__ eposT,
                   const float* __restrict__ eab1, const float* __restrict__ eaW2,
                   const float* __restrict__ eab2, const float* __restrict__ eaW3,
                   const float* __restrict__ eab3,
                   float* __restrict__ attcS, float* __restrict__ attcT, int E)
{
    __shared__ float w2[200], b2s[10], w3s[10], sb1[20], sb3;
    int t = threadIdx.x;
    if (t < 200) w2[t] = eaW2[t];
    if (t < 20)  sb1[t] = eab1[t];
    if (t < 10)  { b2s[t] = eab2[t]; w3s[t] = eaW3[t]; }
    if (t == 0)  sb3 = eab3[0];
    __syncthreads();

    int idx = blockIdx.x * 256 + t;
    if (idx >= 2 * E) return;
    const int g1 = idx >= E;
    const int e  = idx - (g1 ? E : 0);
    const short* P    = g1 ? PT : PS;
    const int*   row  = g1 ? rowT : rowS;
    const int*   col  = g1 ? colT : colS;
    const int*   epos = g1 ? eposT : eposS;
    float*       attc = g1 ? attcT : attcS;

    int r = row[e], c = col[e];
    const unsigned short* p1 = (const unsigned short*)P + (size_t)r * 64;
    const unsigned short* p2 = (const unsigned short*)P + (size_t)c * 64 + 32;

    bh8 a0 = *(const bh8*)&p1[0];
    bh8 a1 = *(const bh8*)&p1[8];
    ushort4 a2 = *(const ushort4*)&p1[16];
    bh8 b0 = *(const bh8*)&p2[0];
    bh8 b1 = *(const bh8*)&p2[8];
    ushort4 b2 = *(const ushort4*)&p2[16];

    float h1[20];
    #pragma unroll
    for (int j = 0; j < 8; ++j)
        h1[j] = relu_f(bf2f((unsigned short)a0[j]) + bf2f((unsigned short)b0[j]) + sb1[j]);
    #pragma unroll
    for (int j = 0; j < 8; ++j)
        h1[8 + j] = relu_f(bf2f((unsigned short)a1[j]) + bf2f((unsigned short)b1[j]) + sb1[8 + j]);
    h1[16] = relu_f(bf2f(a2.x) + bf2f(b2.x) + sb1[16]);
    h1[17] = relu_f(bf2f(a2.y) + bf2f(b2.y) + sb1[17]);
    h1[18] = relu_f(bf2f(a2.z) + bf2f(b2.z) + sb1[18]);
    h1[19] = relu_f(bf2f(a2.w) + bf2f(b2.w) + sb1[19]);

    float h3 = sb3;
    #pragma unroll
    for (int j2 = 0; j2 < 10; ++j2) {
        float s = b2s[j2];
        #pragma unroll
        for (int j = 0; j < 20; ++j)
            s = fmaf(h1[j], w2[j * 10 + j2], s);
        h3 = fmaf(relu_f(s), w3s[j2], h3);
    }
    h3 = relu_f(h3);
    attc[epos[e]] = 1.f / (1.f + expf(-h3));
}

// ---------------------------------------------------------------------------
// CSR build (dual-graph): histogram -> 3-phase scan -> cursor fill (+epos)
// ---------------------------------------------------------------------------
__global__ void hist_both(const int* __restrict__ colS, const int* __restrict__ colT,
                          int* __restrict__ deg, int N, int E)
{
    int idx = blockIdx.x * 256 + threadIdx.x;
    if (idx >= 2 * E) return;
    const int g1 = idx >= E;
    const int e  = idx - (g1 ? E : 0);
    int c = (g1 ? colT : colS)[e];
    atomicAdd(&deg[(size_t)g1 * N + c], 1);
}

__device__ __forceinline__ int block_incl_scan(int v, int* wsum)
{
    int lane = threadIdx.x & 63;
    int w    = threadIdx.x >> 6;
    #pragma unroll
    for (int off = 1; off < 64; off <<= 1) {
        int t = __shfl_up(v, off);
        if (lane >= off) v += t;
    }
    if (lane == 63) wsum[w] = v;
    __syncthreads();
    int add = 0;
    for (int j = 0; j < w; ++j) add += wsum[j];
    return v + add;
}

__global__ __launch_bounds__(256)
void scanA_both(const int* __restrict__ deg, int* __restrict__ coffS,
                int* __restrict__ coffT, int* __restrict__ bsum, int N)
{
    __shared__ int wsum[4];
    int gy = blockIdx.y;
    const int* d = deg + (size_t)gy * N;
    int* coff    = gy ? coffT : coffS;
    int* bs      = bsum + gy * 256;
    int i = blockIdx.x * 256 + threadIdx.x;
    int orig = (i < N) ? d[i] : 0;
    int v = block_incl_scan(orig, wsum);
    if (i < N) coff[i] = v - orig;
    if (threadIdx.x == 255) bs[blockIdx.x] = v;
}

__global__ __launch_bounds__(256)
void scanB_both(const int* __restrict__ bsum, int* __restrict__ boff, int nb)
{
    __shared__ int wsum[4];
    int gy = blockIdx.y;
    const int* bs = bsum + gy * 256;
    int* bo       = boff + gy * 256;
    int tid = threadIdx.x;
    int orig = (tid < nb) ? bs[tid] : 0;
    int v = block_incl_scan(orig, wsum);
    if (tid < nb) bo[tid] = v - orig;
}

__global__ __launch_bounds__(256)
void scanC_both(int* __restrict__ coffS, int* __restrict__ coffT,
                const int* __restrict__ boff, int* __restrict__ curS,
                int* __restrict__ curT, int N, int E)
{
    int gy = blockIdx.y;
    int* coff = gy ? coffT : coffS;
    int* cur  = gy ? curT  : curS;
    const int* bo = boff + gy * 256;
    int i = blockIdx.x * 256 + threadIdx.x;
    if (i < N) {
        int v = coff[i] + bo[i >> 8];
        coff[i] = v;
        cur[i]  = v;
    }
    if (i == 0) coff[N] = E;
}

__global__ __launch_bounds__(256)
void fill_both(const int* __restrict__ rowS, const int* __restrict__ colS,
               const int* __restrict__ rowT, const int* __restrict__ colT,
               int* __restrict__ curS, int* __restrict__ curT,
               int* __restrict__ crowS, int* __restrict__ crowT,
               int* __restrict__ eposS, int* __restrict__ eposT, int E)
{
    int idx = blockIdx.x * 256 + threadIdx.x;
    if (idx >= 2 * E) return;
    const int g1 = idx >= E;
    const int e  = idx - (g1 ? E : 0);
    const int* row = g1 ? rowT : rowS;
    const int* col = g1 ? colT : colS;
    int* cur  = g1 ? curT  : curS;
    int* crow = g1 ? crowT : crowS;
    int* epos = g1 ? eposT : eposS;
    int c = col[e];
    int p = atomicAdd(&cur[c], 1);
    crow[p] = row[e];
    epos[e] = p;
}

// ---------------------------------------------------------------------------
// CSR aggregation (dual-graph, bf16): one wave per node; 4 groups of 16 lanes,
// each group one edge at a time, lane loads 16 B (8 cols). Cross-group
// shfl-reduce at the end. attc/crow stream contiguously (no eid indirection).
// ---------------------------------------------------------------------------
__global__ __launch_bounds__(256)
void agg_both(const short* __restrict__ XbS, const short* __restrict__ XbT,
              const int* __restrict__ coffS, const int* __restrict__ coffT,
              const int* __restrict__ crowS, const int* __restrict__ crowT,
              const float* __restrict__ attcS, const float* __restrict__ attcT,
              short* __restrict__ aggS, short* __restrict__ aggT, int N, int mode)
{
    int ng = blockIdx.x * 4 + (threadIdx.x >> 6);
    if (ng >= 2 * N) return;
    const int g1 = ng >= N;
    const int n  = ng - (g1 ? N : 0);
    const short* Xb   = g1 ? XbT   : XbS;
    const int*   coff = g1 ? coffT : coffS;
    const int*   crow = g1 ? crowT : crowS;
    const float* atc  = g1 ? attcT : attcS;
    short*       aggb = g1 ? aggT  : aggS;

    const int lane = threadIdx.x & 63;
    const int grp  = lane >> 4;
    const int li   = lane & 15;
    const int p0 = coff[n], pe = coff[n + 1];

    float acc[8] = {0.f, 0.f, 0.f, 0.f, 0.f, 0.f, 0.f, 0.f};
    for (int p = p0 + grp; p < pe; p += 4) {
        float a = atc[p];
        float w = mode ? fmaf(-0.5f, a, 1.f) : 0.5f * a;
        int r = crow[p];
        bh8 v = *(const bh8*)&Xb[(size_t)r * 128 + li * 8];
        #pragma unroll
        for (int j = 0; j < 8; ++j)
            acc[j] = fmaf(w, bf2f((unsigned short)v[j]), acc[j]);
    }
    #pragma unroll
    for (int j = 0; j < 8; ++j) acc[j] += __shfl_xor(acc[j], 16);
    #pragma unroll
    for (int j = 0; j < 8; ++j) acc[j] += __shfl_xor(acc[j], 32);
    if (grp == 0) {
        bh8 o;
        #pragma unroll
        for (int j = 0; j < 8; ++j) o[j] = (short)f2bf(acc[j]);
        *(bh8*)&aggb[(size_t)n * 128 + li * 8] = o;
    }
}

// ---------------------------------------------------------------------------

extern "C" void kernel_launch(void* const* d_in, const int* in_sizes, int n_in,
                              void* d_out, int out_size, void* d_ws, size_t ws_size,
                              hipStream_t stream)
{
    const float* src_fea = (const float*)d_in[0];
    const float* trg_fea = (const float*)d_in[1];
    const int*   src_row = (const int*)d_in[2];
    const int*   src_col = (const int*)d_in[3];
    const int*   trg_row = (const int*)d_in[4];
    const int*   trg_col = (const int*)d_in[5];
    const float* fxW1 = (const float*)d_in[6];
    const float* fxb1 = (const float*)d_in[7];
    const float* fxW2 = (const float*)d_in[8];
    const float* fxb2 = (const float*)d_in[9];
    const float* eaW1 = (const float*)d_in[10];
    const float* eab1 = (const float*)d_in[11];
    const float* eaW2 = (const float*)d_in[12];
    const float* eab2 = (const float*)d_in[13];
    const float* eaW3 = (const float*)d_in[14];
    const float* eab3 = (const float*)d_in[15];
    const float* convWroot = (const float*)d_in[16];
    const float* convWrel  = (const float*)d_in[17];

    const int N = in_sizes[0] / 512;
    const int E = in_sizes[2];

    float* out = (float*)d_out;
    const size_t slot_sz = (size_t)N * 128;
    auto slot = [&](int i) { return out + (size_t)i * slot_sz; };

    // ---- workspace layout ----
    float* fp    = (float*)d_ws;
    float* attcS = fp; fp += E;
    float* attcT = fp; fp += E;
    int* ip    = (int*)fp;
    int* deg   = ip; ip += 2 * N;
    int* bsum  = ip; ip += 512;
    int* boff  = ip; ip += 512;
    int* coffS = ip; ip += N + 2;
    int* coffT = ip; ip += N + 2;
    int* curS  = ip; ip += N;
    int* curT  = ip; ip += N;
    int* crowS = ip; ip += E;
    int* crowT = ip; ip += E;
    int* eposS = ip; ip += E;
    int* eposT = ip; ip += E;
    short* sp = (short*)((((uintptr_t)ip) + 255) & ~(uintptr_t)255);
    short* xb0   = sp; sp += slot_sz;            // bf16 src1
    short* xb1   = sp; sp += slot_sz;            // bf16 trg1
    short* xsbS[2]; short* xsbT[2];
    xsbS[0] = sp; sp += slot_sz;
    xsbS[1] = sp; sp += slot_sz;
    xsbT[0] = sp; sp += slot_sz;
    xsbT[1] = sp; sp += slot_sz;
    short* aggS  = sp; sp += slot_sz;
    short* aggT  = sp; sp += slot_sz;
    short* PS    = sp; sp += (size_t)N * 64;     // bf16 projections, stride 64
    short* PT    = sp; sp += (size_t)N * 64;
    short* w56   = sp; sp += 64 * 128;
    short* fxW1t = sp; sp += 128 * 512;
    short* fxW2t = sp; sp += 128 * 128;
    short* wrt   = sp; sp += 2 * 128 * 128;
    short* wlt   = sp; sp += 2 * 128 * 128;

    // ---- weight prep (one kernel) ----
    const int prep_total = 64*128 + 512*128 + 128*128 + 2*128*128 + 2*128*128;
    prep_all<<<(prep_total + 255) / 256, 256, 0, stream>>>(
        eaW1, fxW1, fxW2, convWroot, convWrel, w56, fxW1t, fxW2t, wrt, wlt);

    const int gb = (N + 63) / 64;
    short* hS = xsbS[0];   // fx hidden, dead until L0 conv writes
    short* hT = xsbT[0];
    // fx layer 1+2, both graphs per dispatch
    mfma_gemm<512, 0, 1, false, true, false, true><<<2 * gb, 256, 0, stream>>>(
        src_fea, nullptr, trg_fea, nullptr, fxW1t, nullptr, fxb1,
        nullptr, hS, nullptr, hT, N);
    mfma_gemm<128, 1, 1, false, true, true, true><<<2 * gb, 256, 0, stream>>>(
        hS, nullptr, hT, nullptr, fxW2t, nullptr, fxb2,
        slot(0), xb0, slot(3), xb1, N);

    // ---- CSR build, both graphs ----
    const int e2grid  = (2 * E + 255) / 256;
    const int nchunks = (N + 255) / 256;
    hipMemsetAsync(deg, 0, (size_t)2 * N * sizeof(int), stream);
    hist_both<<<e2grid, 256, 0, stream>>>(src_col, trg_col, deg, N, E);
    scanA_both<<<dim3(nchunks, 2), 256, 0, stream>>>(deg, coffS, coffT, bsum, N);
    scanB_both<<<dim3(1, 2), 256, 0, stream>>>(bsum, boff, nchunks);
    scanC_both<<<dim3(nchunks, 2), 256, 0, stream>>>(coffS, coffT, boff, curS, curT, N, E);
    fill_both<<<e2grid, 256, 0, stream>>>(src_row, src_col, trg_row, trg_col,
                                          curS, curT, crowS, crowT, eposS, eposT, E);

    const int agrid = (2 * N + 3) / 4;

    short* xbS = xb0;
    short* xbT = xb1;
    for (int L = 0; L < 2; ++L) {
        float* xs_s = slot(1 + L);
        float* xs_t = slot(4 + L);
        float* cf_s = slot(6 + L);
        float* cf_t = slot(8 + L);
        const short* WrT = wrt + (size_t)L * 16384;
        const short* WlT = wlt + (size_t)L * 16384;

        // edge attention from current x (bf16), both graphs
        pkern_both<<<2 * gb, 256, 0, stream>>>(xbS, xbT, w56, PS, PT, N);
        edge_att_both<<<e2grid, 256, 0, stream>>>(PS, PT, src_row, src_col,
            trg_row, trg_col, eposS, eposT, eab1, eaW2, eab2, eaW3, eab3,
            attcS, attcT, E);

        // x_new = softsign(x @ Wroot + segsum(wc * x[row]) @ Wrel)
        agg_both<<<agrid, 256, 0, stream>>>(xbS, xbT, coffS, coffT, crowS, crowT,
                                            attcS, attcT, aggS, aggT, N, 0);
        mfma_gemm<128, 1, 2, true, false, true, true><<<2 * gb, 256, 0, stream>>>(
            xbS, aggS, xbT, aggT, WrT, WlT, nullptr,
            xs_s, xsbS[L], xs_t, xsbT[L], N);

        // cfd = softsign(x_new @ Wroot + segsum(wo * x_new[row]) @ Wrel)
        agg_both<<<agrid, 256, 0, stream>>>(xsbS[L], xsbT[L], coffS, coffT,
                                            crowS, crowT, attcS, attcT, aggS, aggT, N, 1);
        mfma_gemm<128, 1, 2, true, false, true, false><<<2 * gb, 256, 0, stream>>>(
            xsbS[L], aggS, xsbT[L], aggT, WrT, WlT, nullptr,
            cf_s, nullptr, cf_t, nullptr, N);

        xbS = xsbS[L];
        xbT = xsbT[L];
    }
}

// Round 6
// 652.678 us; speedup vs baseline: 14.2212x; 1.0570x over previous
//
#include <hip/hip_runtime.h>
#include <math.h>
#include <stdint.h>

// ---------------------------------------------------------------------------
// CANA_nei graph network forward. bf16 MFMA GEMMs; CSR aggregation fused into
// the conv GEMM (gather -> LDS -> MFMA); P-projection fused into the producing
// GEMM's epilogue. Both graphs in every dispatch.
// Output layout: [10, N, 128] = [src1, xs_s0, xs_s1, trg1, xs_t0, xs_t1,
//                                cf_s0, cf_s1, cf_t0, cf_t1]
// ---------------------------------------------------------------------------

typedef __attribute__((ext_vector_type(8))) short bh8;   // 8 bf16 (4 VGPRs)
typedef __attribute__((ext_vector_type(4))) float f4;    // MFMA acc frag

__device__ __forceinline__ float relu_f(float x) { return x > 0.f ? x : 0.f; }

__device__ __forceinline__ unsigned short f2bf(float f) {
    union { float f; unsigned u; } v; v.f = f;
    unsigned r = v.u + 0x7FFF + ((v.u >> 16) & 1);   // RNE
    return (unsigned short)(r >> 16);
}
__device__ __forceinline__ float bf2f(unsigned short b) {
    union { unsigned u; float f; } v; v.u = ((unsigned)b) << 16;
    return v.f;
}

template<int ACT>
__device__ __forceinline__ float act_fn(float x) {
    if (ACT == 1) return 0.5f * x * (1.f + erff(x * 0.70710678118654752f)); // exact GELU
    if (ACT == 2) return x / (1.f + fabsf(x));                              // soft_sign
    return x;
}

// ---------------------------------------------------------------------------
// P-emission phase: As holds xs bf16 [64][136] (A layout), stages W56 [64][128]
// into Bs[64][136], computes P = xs @ W56^T, writes P bf16 stride 64.
// Caller must __syncthreads() + fill As between final MFMA reads and this call.
// ---------------------------------------------------------------------------
__device__ __forceinline__ void emit_p_phase(short* As, short* Bs,
                                             const short* __restrict__ W56,
                                             short* __restrict__ P,
                                             int row0, int M, int t)
{
    #pragma unroll
    for (int p = 0; p < 4; ++p) {
        int idx = t + 256 * p;            // 0..1023
        int r = idx >> 4;                 // 0..63
        int c = (idx & 15) * 8;           // 0..120
        *(bh8*)&Bs[r * 136 + c] = *(const bh8*)(W56 + r * 128 + c);
    }
    __syncthreads();
    const int lane = t & 63, w = t >> 6, l15 = lane & 15, l4 = lane >> 4;
    f4 accP[4];
    #pragma unroll
    for (int ni = 0; ni < 4; ++ni) accP[ni] = (f4){0.f, 0.f, 0.f, 0.f};
    #pragma unroll
    for (int kk = 0; kk < 4; ++kk) {
        bh8 a = *(const bh8*)&As[(w * 16 + l15) * 136 + kk * 32 + l4 * 8];
        #pragma unroll
        for (int ni = 0; ni < 4; ++ni) {
            bh8 b = *(const bh8*)&Bs[(ni * 16 + l15) * 136 + kk * 32 + l4 * 8];
            accP[ni] = __builtin_amdgcn_mfma_f32_16x16x32_bf16(a, b, accP[ni], 0, 0, 0);
        }
    }
    #pragma unroll
    for (int ni = 0; ni < 4; ++ni) {
        int col = ni * 16 + l15;
        #pragma unroll
        for (int r = 0; r < 4; ++r) {
            int row = row0 + w * 16 + l4 * 4 + r;
            if (row < M) P[(size_t)row * 64 + col] = (short)f2bf(accP[ni][r]);
        }
    }
}

// ---------------------------------------------------------------------------
// Plain MFMA GEMM, dual-graph: out[M,128] = act(X @ W + bias).
// X row-major [M,K] (fp32 if AF==0, bf16 if AF==1); Wt pre-transposed bf16
// [128][K]. 64x128 tile, 4 waves (2m x 2n). EMITP: also P = act(..) @ W56^T.
// ---------------------------------------------------------------------------
template<int K, int AF, int ACT, bool BIAS, bool WF32, bool WB16, bool EMITP>
__global__ __launch_bounds__(256, 2)
void mfma_gemm(const void* __restrict__ X0a, const void* __restrict__ X0b,
               const short* __restrict__ W0t, const float* __restrict__ bias,
               float* __restrict__ outfA, short* __restrict__ outbA,
               float* __restrict__ outfB, short* __restrict__ outbB,
               const short* __restrict__ W56,
               short* __restrict__ PA, short* __restrict__ PB, int M)
{
    constexpr int BK  = 64;
    constexpr int LDA = EMITP ? 136 : 72;
    __shared__ short As[64 * LDA];
    __shared__ short Bs[128 * 72];

    const int half = gridDim.x >> 1;
    int bid = blockIdx.x;
    const int g1 = bid >= half;
    bid -= g1 ? half : 0;
    const void* X0v = g1 ? X0b : X0a;
    float* outf = g1 ? outfB : outfA;
    short* outb = g1 ? outbB : outbA;
    short* P    = g1 ? PB : PA;

    const int t    = threadIdx.x;
    const int row0 = bid * 64;
    const int lane = t & 63;
    const int w    = t >> 6;
    const int wr   = w & 1;
    const int wc   = w >> 1;
    const int l15  = lane & 15;
    const int l4   = lane >> 4;

    f4 acc[2][4];
    #pragma unroll
    for (int i = 0; i < 2; ++i)
        #pragma unroll
        for (int j = 0; j < 4; ++j)
            acc[i][j] = (f4){0.f, 0.f, 0.f, 0.f};

    const int ar = t >> 3;
    const int ac = (t & 7) * 8;

    #pragma unroll 1
    for (int k0 = 0; k0 < K; k0 += BK) {
        __syncthreads();
        // stage A tile 64x64
        #pragma unroll
        for (int p = 0; p < 2; ++p) {
            int r    = ar + p * 32;
            int grow = row0 + r;
            bh8 sv = {0, 0, 0, 0, 0, 0, 0, 0};
            if (AF == 0) {
                if (grow < M) {
                    const float* src = (const float*)X0v + (size_t)grow * K + k0 + ac;
                    float4 v0 = *(const float4*)src;
                    float4 v1 = *(const float4*)(src + 4);
                    sv[0] = (short)f2bf(v0.x); sv[1] = (short)f2bf(v0.y);
                    sv[2] = (short)f2bf(v0.z); sv[3] = (short)f2bf(v0.w);
                    sv[4] = (short)f2bf(v1.x); sv[5] = (short)f2bf(v1.y);
                    sv[6] = (short)f2bf(v1.z); sv[7] = (short)f2bf(v1.w);
                }
            } else {
                if (grow < M)
                    sv = *(const bh8*)((const short*)X0v + (size_t)grow * K + k0 + ac);
            }
            *(bh8*)&As[r * LDA + ac] = sv;
        }
        // stage B tile 128x64
        #pragma unroll
        for (int p = 0; p < 4; ++p) {
            int r = ar + p * 32;
            *(bh8*)&Bs[r * 72 + ac] = *(const bh8*)(W0t + (size_t)r * K + k0 + ac);
        }
        __syncthreads();
        #pragma unroll
        for (int kk = 0; kk < 2; ++kk) {
            bh8 a[2], b[4];
            #pragma unroll
            for (int mi = 0; mi < 2; ++mi)
                a[mi] = *(const bh8*)&As[(wr*32 + mi*16 + l15) * LDA + kk*32 + l4*8];
            #pragma unroll
            for (int ni = 0; ni < 4; ++ni)
                b[ni] = *(const bh8*)&Bs[(wc*64 + ni*16 + l15) * 72 + kk*32 + l4*8];
            #pragma unroll
            for (int mi = 0; mi < 2; ++mi)
                #pragma unroll
                for (int ni = 0; ni < 4; ++ni)
                    acc[mi][ni] = __builtin_amdgcn_mfma_f32_16x16x32_bf16(
                        a[mi], b[ni], acc[mi][ni], 0, 0, 0);
        }
    }

    if (EMITP) __syncthreads();          // all LDS reads done before As rewrite
    #pragma unroll
    for (int mi = 0; mi < 2; ++mi) {
        #pragma unroll
        for (int ni = 0; ni < 4; ++ni) {
            int col = wc * 64 + ni * 16 + l15;
            float bv = BIAS ? bias[col] : 0.f;
            #pragma unroll
            for (int r = 0; r < 4; ++r) {
                int rloc = wr * 32 + mi * 16 + l4 * 4 + r;
                int row  = row0 + rloc;
                float v = act_fn<ACT>(acc[mi][ni][r] + bv);
                unsigned short bb = f2bf(v);
                if (row < M) {
                    if (WF32) outf[(size_t)row * 128 + col] = v;
                    if (WB16) outb[(size_t)row * 128 + col] = (short)bb;
                }
                if (EMITP) As[rloc * LDA + col] = (short)bb;
            }
        }
    }
    if (EMITP) emit_p_phase(As, Bs, W56, P, row0, M, t);
}

// ---------------------------------------------------------------------------
// Fused GraphConv: out = softsign(x @ Wroot + agg @ Wrel), dual-graph.
// agg[n] = sum_{p in [coff[n],coff[n+1])} w(attc[p]) * X[crow[p]] computed
// in-kernel into the As LDS tile (no global roundtrip).
// MODE 0: w = 0.5a; MODE 1: w = 1 - 0.5a. EMITP: P = out_bf16 @ W56^T.
// ---------------------------------------------------------------------------
template<int MODE, bool WB16, bool EMITP>
__global__ __launch_bounds__(256, 2)
void conv_fused(const short* __restrict__ XbA, const short* __restrict__ XbB,
                const int* __restrict__ coffA, const int* __restrict__ coffB,
                const int* __restrict__ crowA, const int* __restrict__ crowB,
                const float* __restrict__ attcA, const float* __restrict__ attcB,
                const short* __restrict__ Wroot, const short* __restrict__ Wrel,
                const short* __restrict__ W56,
                float* __restrict__ outfA, float* __restrict__ outfB,
                short* __restrict__ outbA, short* __restrict__ outbB,
                short* __restrict__ PA, short* __restrict__ PB, int M)
{
    constexpr int LDA = 136;             // full-K agg tile [64][136]
    __shared__ short As[64 * LDA];
    __shared__ short Bs[128 * 72];

    const int half = gridDim.x >> 1;
    int bid = blockIdx.x;
    const int g1 = bid >= half;
    bid -= g1 ? half : 0;
    const short* Xb   = g1 ? XbB   : XbA;
    const int*   coff = g1 ? coffB : coffA;
    const int*   crow = g1 ? crowB : crowA;
    const float* attc = g1 ? attcB : attcA;
    float* outf = g1 ? outfB : outfA;
    short* outb = g1 ? outbB : outbA;
    short* P    = g1 ? PB : PA;

    const int t    = threadIdx.x;
    const int row0 = bid * 64;
    const int lane = t & 63;
    const int w    = t >> 6;
    const int wr   = w & 1;
    const int wc   = w >> 1;
    const int l15  = lane & 15;
    const int l4   = lane >> 4;

    // ---- Phase 1: CSR gather -> agg tile in As (bf16, A layout) ----
    {
        const int g  = t >> 4;           // 16 groups
        const int li = t & 15;
        #pragma unroll 1
        for (int q = 0; q < 4; ++q) {
            int rloc = g * 4 + q;
            int n = row0 + rloc;
            float a8[8] = {0.f, 0.f, 0.f, 0.f, 0.f, 0.f, 0.f, 0.f};
            if (n < M) {
                int p  = coff[n];
                int pe = coff[n + 1];
                for (; p + 3 < pe; p += 4) {
                    float w0 = attc[p],     w1 = attc[p + 1];
                    float w2 = attc[p + 2], w3 = attc[p + 3];
                    int r0 = crow[p],     r1 = crow[p + 1];
                    int r2 = crow[p + 2], r3 = crow[p + 3];
                    w0 = MODE ? fmaf(-0.5f, w0, 1.f) : 0.5f * w0;
                    w1 = MODE ? fmaf(-0.5f, w1, 1.f) : 0.5f * w1;
                    w2 = MODE ? fmaf(-0.5f, w2, 1.f) : 0.5f * w2;
                    w3 = MODE ? fmaf(-0.5f, w3, 1.f) : 0.5f * w3;
                    bh8 v0 = *(const bh8*)&Xb[(size_t)r0 * 128 + li * 8];
                    bh8 v1 = *(const bh8*)&Xb[(size_t)r1 * 128 + li * 8];
                    bh8 v2 = *(const bh8*)&Xb[(size_t)r2 * 128 + li * 8];
                    bh8 v3 = *(const bh8*)&Xb[(size_t)r3 * 128 + li * 8];
                    #pragma unroll
                    for (int j = 0; j < 8; ++j) {
                        a8[j] = fmaf(w0, bf2f((unsigned short)v0[j]), a8[j]);
                        a8[j] = fmaf(w1, bf2f((unsigned short)v1[j]), a8[j]);
                        a8[j] = fmaf(w2, bf2f((unsigned short)v2[j]), a8[j]);
                        a8[j] = fmaf(w3, bf2f((unsigned short)v3[j]), a8[j]);
                    }
                }
                for (; p < pe; ++p) {
                    float w0 = attc[p];
                    int   r0 = crow[p];
                    w0 = MODE ? fmaf(-0.5f, w0, 1.f) : 0.5f * w0;
                    bh8 v0 = *(const bh8*)&Xb[(size_t)r0 * 128 + li * 8];
                    #pragma unroll
                    for (int j = 0; j < 8; ++j)
                        a8[j] = fmaf(w0, bf2f((unsigned short)v0[j]), a8[j]);
                }
            }
            bh8 o;
            #pragma unroll
            for (int j = 0; j < 8; ++j) o[j] = (short)f2bf(a8[j]);
            *(bh8*)&As[rloc * LDA + li * 8] = o;
        }
    }
    __syncthreads();

    f4 acc[2][4];
    #pragma unroll
    for (int i = 0; i < 2; ++i)
        #pragma unroll
        for (int j = 0; j < 4; ++j)
            acc[i][j] = (f4){0.f, 0.f, 0.f, 0.f};

    const int ar = t >> 3;
    const int ac = (t & 7) * 8;

    // ---- Phase 2: agg @ Wrel (As stable, Bs staged per k-step) ----
    #pragma unroll 1
    for (int k0 = 0; k0 < 128; k0 += 64) {
        if (k0) __syncthreads();
        #pragma unroll
        for (int p = 0; p < 4; ++p) {
            int r = ar + p * 32;
            *(bh8*)&Bs[r * 72 + ac] = *(const bh8*)(Wrel + (size_t)r * 128 + k0 + ac);
        }
        __syncthreads();
        #pragma unroll
        for (int kk = 0; kk < 2; ++kk) {
            bh8 a[2], b[4];
            #pragma unroll
            for (int mi = 0; mi < 2; ++mi)
                a[mi] = *(const bh8*)&As[(wr*32 + mi*16 + l15) * LDA + k0 + kk*32 + l4*8];
            #pragma unroll
            for (int ni = 0; ni < 4; ++ni)
                b[ni] = *(const bh8*)&Bs[(wc*64 + ni*16 + l15) * 72 + kk*32 + l4*8];
            #pragma unroll
            for (int mi = 0; mi < 2; ++mi)
                #pragma unroll
                for (int ni = 0; ni < 4; ++ni)
                    acc[mi][ni] = __builtin_amdgcn_mfma_f32_16x16x32_bf16(
                        a[mi], b[ni], acc[mi][ni], 0, 0, 0);
        }
    }

    // ---- Phase 3: x @ Wroot (As cols 0..63 restaged per k-step) ----
    #pragma unroll 1
    for (int k0 = 0; k0 < 128; k0 += 64) {
        __syncthreads();
        #pragma unroll
        for (int p = 0; p < 2; ++p) {
            int r    = ar + p * 32;
            int grow = row0 + r;
            bh8 sv = {0, 0, 0, 0, 0, 0, 0, 0};
            if (grow < M)
                sv = *(const bh8*)(Xb + (size_t)grow * 128 + k0 + ac);
            *(bh8*)&As[r * LDA + ac] = sv;
        }
        #pragma unroll
        for (int p = 0; p < 4; ++p) {
            int r = ar + p * 32;
            *(bh8*)&Bs[r * 72 + ac] = *(const bh8*)(Wroot + (size_t)r * 128 + k0 + ac);
        }
        __syncthreads();
        #pragma unroll
        for (int kk = 0; kk < 2; ++kk) {
            bh8 a[2], b[4];
            #pragma unroll
            for (int mi = 0; mi < 2; ++mi)
                a[mi] = *(const bh8*)&As[(wr*32 + mi*16 + l15) * LDA + kk*32 + l4*8];
            #pragma unroll
            for (int ni = 0; ni < 4; ++ni)
                b[ni] = *(const bh8*)&Bs[(wc*64 + ni*16 + l15) * 72 + kk*32 + l4*8];
            #pragma unroll
            for (int mi = 0; mi < 2; ++mi)
                #pragma unroll
                for (int ni = 0; ni < 4; ++ni)
                    acc[mi][ni] = __builtin_amdgcn_mfma_f32_16x16x32_bf16(
                        a[mi], b[ni], acc[mi][ni], 0, 0, 0);
        }
    }

    // ---- Epilogue (+ optional P emission) ----
    if (EMITP) __syncthreads();
    #pragma unroll
    for (int mi = 0; mi < 2; ++mi) {
        #pragma unroll
        for (int ni = 0; ni < 4; ++ni) {
            int col = wc * 64 + ni * 16 + l15;
            #pragma unroll
            for (int r = 0; r < 4; ++r) {
                int rloc = wr * 32 + mi * 16 + l4 * 4 + r;
                int row  = row0 + rloc;
                float v = act_fn<2>(acc[mi][ni][r]);
                unsigned short bb = f2bf(v);
                if (row < M) {
                    outf[(size_t)row * 128 + col] = v;
                    if (WB16) outb[(size_t)row * 128 + col] = (short)bb;
                }
                if (EMITP) As[rloc * LDA + col] = (short)bb;
            }
        }
    }
    if (EMITP) emit_p_phase(As, Bs, W56, P, row0, M, t);
}

// ---------------------------------------------------------------------------
// One-shot weight prep: w56 + all bf16 transposed weights.
// ---------------------------------------------------------------------------
__global__ void prep_all(const float* __restrict__ eaW1, const float* __restrict__ fxW1,
                         const float* __restrict__ fxW2, const float* __restrict__ convWroot,
                         const float* __restrict__ convWrel,
                         short* __restrict__ w56, short* __restrict__ fxW1t,
                         short* __restrict__ fxW2t, short* __restrict__ wrt,
                         short* __restrict__ wlt)
{
    int i = blockIdx.x * 256 + threadIdx.x;
    if (i < 64 * 128) {
        int j = i >> 7, k = i & 127;
        float v = 0.f;
        if (j < 20)                  v = eaW1[k * 20 + j];
        else if (j >= 32 && j < 52)  v = eaW1[(128 + k) * 20 + (j - 32)];
        w56[i] = (short)f2bf(v);
        return;
    }
    i -= 64 * 128;
    if (i < 512 * 128) {
        int k = i >> 7, n = i & 127;
        fxW1t[(size_t)n * 512 + k] = (short)f2bf(fxW1[i]);
        return;
    }
    i -= 512 * 128;
    if (i < 128 * 128) {
        int k = i >> 7, n = i & 127;
        fxW2t[n * 128 + k] = (short)f2bf(fxW2[i]);
        return;
    }
    i -= 128 * 128;
    if (i < 2 * 128 * 128) {
        int L = i >> 14, r = i & 16383;
        int k = r >> 7, n = r & 127;
        wrt[L * 16384 + n * 128 + k] = (short)f2bf(convWroot[i]);
        return;
    }
    i -= 2 * 128 * 128;
    if (i < 2 * 128 * 128) {
        int L = i >> 14, r = i & 16383;
        int k = r >> 7, n = r & 127;
        wlt[L * 16384 + n * 128 + k] = (short)f2bf(convWrel[i]);
    }
}

// ---------------------------------------------------------------------------
// Edge attention tail (dual-graph, vectorized bf16 P gather).
// Writes att directly in CSR order: attc[epos[e]] = sigmoid(...)
// ---------------------------------------------------------------------------
__global__ __launch_bounds__(256)
void edge_att_both(const short* __restrict__ PS, const short* __restrict__ PT,
                   const int* __restrict__ rowS, const int* __restrict__ colS,
                   const int* __restrict__ rowT, const int* __restrict__ colT,
                   const int* __restrict__ eposS, const int* __restrict__ eposT,
                   const float* __restrict__ eab1, const float* __restrict__ eaW2,
                   const float* __restrict__ eab2, const float* __restrict__ eaW3,
                   const float* __restrict__ eab3,
                   float* __restrict__ attcS, float* __restrict__ attcT, int E)
{
    __shared__ float w2[200], b2s[10], w3s[10], sb1[20], sb3;
    int t = threadIdx.x;
    if (t < 200) w2[t] = eaW2[t];
    if (t < 20)  sb1[t] = eab1[t];
    if (t < 10)  { b2s[t] = eab2[t]; w3s[t] = eaW3[t]; }
    if (t == 0)  sb3 = eab3[0];
    __syncthreads();

    int idx = blockIdx.x * 256 + t;
    if (idx >= 2 * E) return;
    const int g1 = idx >= E;
    const int e  = idx - (g1 ? E : 0);
    const short* P    = g1 ? PT : PS;
    const int*   row  = g1 ? rowT : rowS;
    const int*   col  = g1 ? colT : colS;
    const int*   epos = g1 ? eposT : eposS;
    float*       attc = g1 ? attcT : attcS;

    int r = row[e], c = col[e];
    const unsigned short* p1 = (const unsigned short*)P + (size_t)r * 64;
    const unsigned short* p2 = (const unsigned short*)P + (size_t)c * 64 + 32;

    bh8 a0 = *(const bh8*)&p1[0];
    bh8 a1 = *(const bh8*)&p1[8];
    ushort4 a2 = *(const ushort4*)&p1[16];
    bh8 b0 = *(const bh8*)&p2[0];
    bh8 b1 = *(const bh8*)&p2[8];
    ushort4 b2 = *(const ushort4*)&p2[16];

    float h1[20];
    #pragma unroll
    for (int j = 0; j < 8; ++j)
        h1[j] = relu_f(bf2f((unsigned short)a0[j]) + bf2f((unsigned short)b0[j]) + sb1[j]);
    #pragma unroll
    for (int j = 0; j < 8; ++j)
        h1[8 + j] = relu_f(bf2f((unsigned short)a1[j]) + bf2f((unsigned short)b1[j]) + sb1[8 + j]);
    h1[16] = relu_f(bf2f(a2.x) + bf2f(b2.x) + sb1[16]);
    h1[17] = relu_f(bf2f(a2.y) + bf2f(b2.y) + sb1[17]);
    h1[18] = relu_f(bf2f(a2.z) + bf2f(b2.z) + sb1[18]);
    h1[19] = relu_f(bf2f(a2.w) + bf2f(b2.w) + sb1[19]);

    float h3 = sb3;
    #pragma unroll
    for (int j2 = 0; j2 < 10; ++j2) {
        float s = b2s[j2];
        #pragma unroll
        for (int j = 0; j < 20; ++j)
            s = fmaf(h1[j], w2[j * 10 + j2], s);
        h3 = fmaf(relu_f(s), w3s[j2], h3);
    }
    h3 = relu_f(h3);
    attc[epos[e]] = 1.f / (1.f + expf(-h3));
}

// ---------------------------------------------------------------------------
// CSR build (dual-graph): histogram -> 3-phase scan -> cursor fill (+epos)
// ---------------------------------------------------------------------------
__global__ void hist_both(const int* __restrict__ colS, const int* __restrict__ colT,
                          int* __restrict__ deg, int N, int E)
{
    int idx = blockIdx.x * 256 + threadIdx.x;
    if (idx >= 2 * E) return;
    const int g1 = idx >= E;
    const int e  = idx - (g1 ? E : 0);
    int c = (g1 ? colT : colS)[e];
    atomicAdd(&deg[(size_t)g1 * N + c], 1);
}

__device__ __forceinline__ int block_incl_scan(int v, int* wsum)
{
    int lane = threadIdx.x & 63;
    int w    = threadIdx.x >> 6;
    #pragma unroll
    for (int off = 1; off < 64; off <<= 1) {
        int t = __shfl_up(v, off);
        if (lane >= off) v += t;
    }
    if (lane == 63) wsum[w] = v;
    __syncthreads();
    int add = 0;
    for (int j = 0; j < w; ++j) add += wsum[j];
    return v + add;
}

__global__ __launch_bounds__(256)
void scanA_both(const int* __restrict__ deg, int* __restrict__ coffS,
                int* __restrict__ coffT, int* __restrict__ bsum, int N)
{
    __shared__ int wsum[4];
    int gy = blockIdx.y;
    const int* d = deg + (size_t)gy * N;
    int* coff    = gy ? coffT : coffS;
    int* bs      = bsum + gy * 256;
    int i = blockIdx.x * 256 + threadIdx.x;
    int orig = (i < N) ? d[i] : 0;
    int v = block_incl_scan(orig, wsum);
    if (i < N) coff[i] = v - orig;
    if (threadIdx.x == 255) bs[blockIdx.x] = v;
}

__global__ __launch_bounds__(256)
void scanB_both(const int* __restrict__ bsum, int* __restrict__ boff, int nb)
{
    __shared__ int wsum[4];
    int gy = blockIdx.y;
    const int* bs = bsum + gy * 256;
    int* bo       = boff + gy * 256;
    int tid = threadIdx.x;
    int orig = (tid < nb) ? bs[tid] : 0;
    int v = block_incl_scan(orig, wsum);
    if (tid < nb) bo[tid] = v - orig;
}

__global__ __launch_bounds__(256)
void scanC_both(int* __restrict__ coffS, int* __restrict__ coffT,
                const int* __restrict__ boff, int* __restrict__ curS,
                int* __restrict__ curT, int N, int E)
{
    int gy = blockIdx.y;
    int* coff = gy ? coffT : coffS;
    int* cur  = gy ? curT  : curS;
    const int* bo = boff + gy * 256;
    int i = blockIdx.x * 256 + threadIdx.x;
    if (i < N) {
        int v = coff[i] + bo[i >> 8];
        coff[i] = v;
        cur[i]  = v;
    }
    if (i == 0) coff[N] = E;
}

__global__ __launch_bounds__(256)
void fill_both(const int* __restrict__ rowS, const int* __restrict__ colS,
               const int* __restrict__ rowT, const int* __restrict__ colT,
               int* __restrict__ curS, int* __restrict__ curT,
               int* __restrict__ crowS, int* __restrict__ crowT,
               int* __restrict__ eposS, int* __restrict__ eposT, int E)
{
    int idx = blockIdx.x * 256 + threadIdx.x;
    if (idx >= 2 * E) return;
    const int g1 = idx >= E;
    const int e  = idx - (g1 ? E : 0);
    const int* row = g1 ? rowT : rowS;
    const int* col = g1 ? colT : colS;
    int* cur  = g1 ? curT  : curS;
    int* crow = g1 ? crowT : crowS;
    int* epos = g1 ? eposT : eposS;
    int c = col[e];
    int p = atomicAdd(&cur[c], 1);
    crow[p] = row[e];
    epos[e] = p;
}

// ---------------------------------------------------------------------------

extern "C" void kernel_launch(void* const* d_in, const int* in_sizes, int n_in,
                              void* d_out, int out_size, void* d_ws, size_t ws_size,
                              hipStream_t stream)
{
    const float* src_fea = (const float*)d_in[0];
    const float* trg_fea = (const float*)d_in[1];
    const int*   src_row = (const int*)d_in[2];
    const int*   src_col = (const int*)d_in[3];
    const int*   trg_row = (const int*)d_in[4];
    const int*   trg_col = (const int*)d_in[5];
    const float* fxW1 = (const float*)d_in[6];
    const float* fxb1 = (const float*)d_in[7];
    const float* fxW2 = (const float*)d_in[8];
    const float* fxb2 = (const float*)d_in[9];
    const float* eaW1 = (const float*)d_in[10];
    const float* eab1 = (const float*)d_in[11];
    const float* eaW2 = (const float*)d_in[12];
    const float* eab2 = (const float*)d_in[13];
    const float* eaW3 = (const float*)d_in[14];
    const float* eab3 = (const float*)d_in[15];
    const float* convWroot = (const float*)d_in[16];
    const float* convWrel  = (const float*)d_in[17];

    const int N = in_sizes[0] / 512;
    const int E = in_sizes[2];

    float* out = (float*)d_out;
    const size_t slot_sz = (size_t)N * 128;
    auto slot = [&](int i) { return out + (size_t)i * slot_sz; };

    // ---- workspace layout ----
    float* fp    = (float*)d_ws;
    float* attcS = fp; fp += E;
    float* attcT = fp; fp += E;
    int* ip    = (int*)fp;
    int* deg   = ip; ip += 2 * N;
    int* bsum  = ip; ip += 512;
    int* boff  = ip; ip += 512;
    int* coffS = ip; ip += N + 2;
    int* coffT = ip; ip += N + 2;
    int* curS  = ip; ip += N;
    int* curT  = ip; ip += N;
    int* crowS = ip; ip += E;
    int* crowT = ip; ip += E;
    int* eposS = ip; ip += E;
    int* eposT = ip; ip += E;
    short* sp = (short*)((((uintptr_t)ip) + 255) & ~(uintptr_t)255);
    short* xb0   = sp; sp += slot_sz;            // bf16 src1
    short* xb1   = sp; sp += slot_sz;            // bf16 trg1
    short* xsbS[2]; short* xsbT[2];
    xsbS[0] = sp; sp += slot_sz;
    xsbS[1] = sp; sp += slot_sz;
    xsbT[0] = sp; sp += slot_sz;
    xsbT[1] = sp; sp += slot_sz;
    short* PS    = sp; sp += (size_t)N * 64;     // bf16 projections, stride 64
    short* PT    = sp; sp += (size_t)N * 64;
    short* w56   = sp; sp += 64 * 128;
    short* fxW1t = sp; sp += 128 * 512;
    short* fxW2t = sp; sp += 128 * 128;
    short* wrt   = sp; sp += 2 * 128 * 128;
    short* wlt   = sp; sp += 2 * 128 * 128;

    // ---- weight prep ----
    const int prep_total = 64*128 + 512*128 + 128*128 + 2*128*128 + 2*128*128;
    prep_all<<<(prep_total + 255) / 256, 256, 0, stream>>>(
        eaW1, fxW1, fxW2, convWroot, convWrel, w56, fxW1t, fxW2t, wrt, wlt);

    const int gb = (N + 63) / 64;
    short* hS = xsbS[0];   // fx hidden, dead until L0 conv writes
    short* hT = xsbT[0];
    // fx layer 1 (fp32 in, bf16 h out)
    mfma_gemm<512, 0, 1, true, false, true, false><<<2 * gb, 256, 0, stream>>>(
        src_fea, trg_fea, fxW1t, fxb1,
        nullptr, hS, nullptr, hT, nullptr, nullptr, nullptr, N);
    // fx layer 2 (+ emit P for L0 edge attention)
    mfma_gemm<128, 1, 1, true, true, true, true><<<2 * gb, 256, 0, stream>>>(
        hS, hT, fxW2t, fxb2,
        slot(0), xb0, slot(3), xb1, w56, PS, PT, N);

    // ---- CSR build, both graphs ----
    const int e2grid  = (2 * E + 255) / 256;
    const int nchunks = (N + 255) / 256;
    hipMemsetAsync(deg, 0, (size_t)2 * N * sizeof(int), stream);
    hist_both<<<e2grid, 256, 0, stream>>>(src_col, trg_col, deg, N, E);
    scanA_both<<<dim3(nchunks, 2), 256, 0, stream>>>(deg, coffS, coffT, bsum, N);
    scanB_both<<<dim3(1, 2), 256, 0, stream>>>(bsum, boff, nchunks);
    scanC_both<<<dim3(nchunks, 2), 256, 0, stream>>>(coffS, coffT, boff, curS, curT, N, E);
    fill_both<<<e2grid, 256, 0, stream>>>(src_row, src_col, trg_row, trg_col,
                                          curS, curT, crowS, crowT, eposS, eposT, E);

    short* xbS = xb0;
    short* xbT = xb1;
    for (int L = 0; L < 2; ++L) {
        float* xs_s = slot(1 + L);
        float* xs_t = slot(4 + L);
        float* cf_s = slot(6 + L);
        float* cf_t = slot(8 + L);
        const short* WrT = wrt + (size_t)L * 16384;
        const short* WlT = wlt + (size_t)L * 16384;

        // edge attention from P(x)
        edge_att_both<<<e2grid, 256, 0, stream>>>(PS, PT, src_row, src_col,
            trg_row, trg_col, eposS, eposT, eab1, eaW2, eab2, eaW3, eab3,
            attcS, attcT, E);

        // x_new = softsign(x @ Wroot + agg_wc @ Wrel); L0 also emits P(x_new)
        if (L == 0)
            conv_fused<0, true, true><<<2 * gb, 256, 0, stream>>>(
                xbS, xbT, coffS, coffT, crowS, crowT, attcS, attcT,
                WrT, WlT, w56, xs_s, xs_t, xsbS[L], xsbT[L], PS, PT, N);
        else
            conv_fused<0, true, false><<<2 * gb, 256, 0, stream>>>(
                xbS, xbT, coffS, coffT, crowS, crowT, attcS, attcT,
                WrT, WlT, nullptr, xs_s, xs_t, xsbS[L], xsbT[L], nullptr, nullptr, N);

        // cfd = softsign(x_new @ Wroot + agg_wo @ Wrel)
        conv_fused<1, false, false><<<2 * gb, 256, 0, stream>>>(
            xsbS[L], xsbT[L], coffS, coffT, crowS, crowT, attcS, attcT,
            WrT, WlT, nullptr, cf_s, cf_t, nullptr, nullptr, nullptr, nullptr, N);

        xbS = xsbS[L];
        xbT = xsbT[L];
    }
}